// Round 3
// baseline (457.729 us; speedup 1.0000x reference)
//
#include <hip/hip_runtime.h>

constexpr float F_Y0     = 0.28209479177387814f;
constexpr float F_CUTOFF = 4.6f;

typedef short short8 __attribute__((ext_vector_type(8)));
typedef float f32x4  __attribute__((ext_vector_type(4)));
typedef float float2v __attribute__((ext_vector_type(2)));

__device__ __forceinline__ float siluf(float v) { return v / (1.0f + __expf(-v)); }

// gfx950 hardware packed fp32->bf16 (RNE): lo = cvt(a), hi = cvt(b)
__device__ __forceinline__ unsigned pk2(float a, float b) {
  unsigned r;
  asm("v_cvt_pk_bf16_f32 %0, %1, %2" : "=v"(r) : "v"(a), "v"(b));
  return r;
}
// extract bf16 half h (0=lo,1=hi) of dword d as fp32
__device__ __forceinline__ float xbf(unsigned d, int h) {
  return __uint_as_float(h ? (d & 0xffff0000u) : (d << 16));
}
// packed fp32 multiply (full-rate VOP3P on CDNA)
__device__ __forceinline__ float2v pkmul2(float2v a, float2v b) {
  float2v d;
  asm("v_pk_mul_f32 %0, %1, %2" : "=v"(d) : "v"(a), "v"(b));
  return d;
}

union FragU { uint4 u; short8 s; };

__device__ __forceinline__ void load16(const float* p, float* r) {
  const float4* p4 = (const float4*)p;
#pragma unroll
  for (int i = 0; i < 4; i++) {
    float4 t = p4[i];
    r[4*i] = t.x; r[4*i+1] = t.y; r[4*i+2] = t.z; r[4*i+3] = t.w;
  }
}
__device__ __forceinline__ void store16(float* p, const float* r) {
  float4* p4 = (float4*)p;
#pragma unroll
  for (int i = 0; i < 4; i++) p4[i] = make_float4(r[4*i], r[4*i+1], r[4*i+2], r[4*i+3]);
}

// block-level sum of one float per thread -> part[blockIdx.x]
__device__ __forceinline__ void block_reduce_store(float v, float* part) {
  __shared__ float sred[4];
  int tid = threadIdx.x;
#pragma unroll
  for (int off = 32; off > 0; off >>= 1) v += __shfl_down(v, off, 64);
  if ((tid & 63) == 0) sred[tid >> 6] = v;
  __syncthreads();
  if (tid == 0) part[blockIdx.x] = sred[0] + sred[1] + sred[2] + sred[3];
}

// ---------------- per-edge precompute (+ CSR histogram fused) ----------------
__global__ __launch_bounds__(256) void k_pre(
    const int* __restrict__ species, const int* __restrict__ src, const int* __restrict__ dst,
    const float* __restrict__ rel_pos,
    float* __restrict__ dist_, float* __restrict__ scale_,
    int* __restrict__ cnt,
    float* __restrict__ coul_part, int E)
{
  int e = blockIdx.x * 256 + threadIdx.x;
  float ce = 0.0f;
  if (e < E) {
    float px = rel_pos[3*(size_t)e + 0];
    float py = rel_pos[3*(size_t)e + 1];
    float pz = rel_pos[3*(size_t)e + 2];
    float dist = sqrtf(px*px + py*py + pz*pz);
    float xc = dist * (1.0f / F_CUTOFF);
    bool in_cut = dist < F_CUTOFF;
    float x2 = in_cut ? xc * xc : 0.0f;
    x2 = fminf(x2, 1.0f - 1e-6f);
    float sc = in_cut ? __expf(3.0f - 3.0f / (1.0f - x2)) : 0.0f;
    dist_[e] = dist;
    scale_[e] = sc;
    atomicAdd(&cnt[dst[e]], 1);
    float Zu = (float)species[src[e]];
    float Zv = (float)species[dst[e]];
    float raw = 0.529f * Zu * Zv / (2.0f * dist);
    float au = 0.8854f * 0.529f / (__powf(Zu, 0.23f) + __powf(Zv, 0.23f));
    float xx = dist / au;
    float screen = 0.1818f   * __expf(-3.2f    * xx)
                 + 0.5099f   * __expf(-0.9423f * xx)
                 + 0.2802f   * __expf(-0.4028f * xx)
                 + 0.02817f  * __expf(-0.2016f * xx);
    ce = raw * screen * sc;
  }
  block_reduce_store(ce, coul_part);
}

// ---------------- CSR scans ----------------
__global__ __launch_bounds__(256) void k_scan1(
    const int* __restrict__ cnt, int* __restrict__ row_ptr, int* __restrict__ bsum)
{
  __shared__ int s[256];
  int tid = threadIdx.x;
  int n = blockIdx.x * 256 + tid;
  int v = cnt[n];
  s[tid] = v;
  __syncthreads();
#pragma unroll
  for (int off = 1; off < 256; off <<= 1) {
    int t = (tid >= off) ? s[tid - off] : 0;
    __syncthreads();
    s[tid] += t;
    __syncthreads();
  }
  row_ptr[n] = s[tid] - v;
  if (tid == 255) bsum[blockIdx.x] = s[255];
}

__global__ __launch_bounds__(128) void k_scan2(int* __restrict__ bsum, int* __restrict__ boff)
{
  __shared__ int s[128];
  int tid = threadIdx.x;
  int v = bsum[tid];
  s[tid] = v;
  __syncthreads();
#pragma unroll
  for (int off = 1; off < 128; off <<= 1) {
    int t = (tid >= off) ? s[tid - off] : 0;
    __syncthreads();
    s[tid] += t;
    __syncthreads();
  }
  boff[tid] = s[tid] - v;
}

__global__ __launch_bounds__(256) void k_scan3(
    int* __restrict__ row_ptr, int* __restrict__ row_cur,
    const int* __restrict__ boff, int N, int E)
{
  int n = blockIdx.x * 256 + threadIdx.x;
  int rp = row_ptr[n] + boff[blockIdx.x];
  row_ptr[n] = rp;
  row_cur[n] = rp;
  if (n == 0) row_ptr[N] = E;
}

// scatter payload directly to permuted position (k_permute fused away)
__global__ __launch_bounds__(256) void k_scatter_perm(
    const int* __restrict__ src, const int* __restrict__ dst,
    const float* __restrict__ dist_, const float* __restrict__ scale_,
    int* __restrict__ row_cur,
    int* __restrict__ srcP, float* __restrict__ distP, float* __restrict__ scaleP, int E)
{
  int e = blockIdx.x * 256 + threadIdx.x;
  if (e >= E) return;
  int pos = atomicAdd(&row_cur[dst[e]], 1);
  srcP[pos]   = src[e];
  distP[pos]  = dist_[e];
  scaleP[pos] = scale_[e];
}

// ---------------- weight prepack: per layer 21 bf16 B-fragments ----------------
// NOTE: W2 fragments (f=17,18) are k-interleaved to match the pair layout
// (m, m+16) that h1 is stored in: physical k position p holds logical
// row m(p) = (p&1) ? 16+(p>>1) : (p>>1).
__global__ __launch_bounds__(256) void k_prepack(
    const float* __restrict__ kv_W3, const float* __restrict__ kv_b3,
    const float* __restrict__ fin_W3, const float* __restrict__ fin_b3,
    const float* __restrict__ kv_W2, const float* __restrict__ fin_W2,
    const float* __restrict__ kv_W1, const float* __restrict__ fin_W1,
    uint4* __restrict__ WF)
{
  int t = blockIdx.x * 256 + threadIdx.x;
  if (t >= 5 * 21 * 64) return;
  int lyr = t / (21 * 64);
  int rem = t - lyr * 21 * 64;
  int f = rem >> 6;
  int l = rem & 63;
  int qq = l >> 4;
  int o = l & 15;
  const float* W3 = (lyr < 4) ? (kv_W3 + (size_t)lyr * 32 * 256) : fin_W3;
  const float* B3 = (lyr < 4) ? (kv_b3 + (size_t)lyr * 256) : fin_b3;
  const float* W2 = (lyr < 4) ? (kv_W2 + (size_t)lyr * 32 * 32) : fin_W2;
  const float* W1 = (lyr < 4) ? (kv_W1 + (size_t)lyr * 16 * 32) : fin_W1;
  float v[8];
#pragma unroll
  for (int j = 0; j < 8; j++) {
    if (f < 16) {
      int kk = f * 32 + qq * 8 + j;
      int m = kk >> 4, i = kk & 15;
      v[j] = W3[m * 256 + o * 16 + i];
    } else if (f == 16) {
      int r = qq * 8 + j;
      int mp = r >> 4, i = r & 15;
      v[j] = mp ? 0.0f : B3[o * 16 + i];
    } else if (f < 19) {
      int c = f - 17;
      int p = qq * 8 + j;                       // physical k position
      int m = (p & 1) ? (16 + (p >> 1)) : (p >> 1);  // pair-interleave
      v[j] = W2[m * 32 + c * 16 + o];
    } else {
      int c = f - 19;
      int k = qq * 8 + j;
      v[j] = (k < 16) ? W1[k * 32 + c * 16 + o] : 0.0f;
    }
  }
  uint4 dw;
  dw.x = pk2(v[0], v[1]);
  dw.y = pk2(v[2], v[3]);
  dw.z = pk2(v[4], v[5]);
  dw.w = pk2(v[6], v[7]);
  WF[t] = dw;
}

// ---------------- node init (x, q0; semb read on-demand later) ----------------
__global__ __launch_bounds__(256) void k_node_init(
    const int* __restrict__ species, const float* __restrict__ emb,
    const float* __restrict__ Wq0,
    float* __restrict__ x, float* __restrict__ q, int N)
{
  int n = blockIdx.x * 256 + threadIdx.x;
  if (n >= N) return;
  int sp = species[n] - 1;
  float xv[16];
  load16(emb + (size_t)sp * 16, xv);
  store16(x + (size_t)n * 16, xv);
  float qv[8];
#pragma unroll
  for (int h = 0; h < 8; h++) {
    float a = 0.f;
#pragma unroll
    for (int i = 0; i < 16; i++) a += Wq0[h * 16 + i] * xv[i];
    qv[h] = a;
  }
  float4* qp = (float4*)(q + (size_t)n * 8);
  qp[0] = make_float4(qv[0], qv[1], qv[2], qv[3]);
  qp[1] = make_float4(qv[4], qv[5], qv[6], qv[7]);
}

// ---------------- heavy edge conv: WAVE-LOCAL, zero __syncthreads ----------
// Each wave owns 16 edges end-to-end in a wave-private LDS region.
// LDS aliasing: P [0,1024) overlays the staging buffers {xsS,xsB,efB,h1P},
// which are all dead before the first P write (consumed by the h1/h2 MFMAs
// or pulled into registers: xs2, bias A-frag, hmv). Same-wave DS ops are
// processed in issue order and every P-write's data has a true register
// dependency on those reads, so the WAR overlap is safe.
// Per-wave: 1344 dw = 5376 B; block = 21504 B -> 7 blocks/CU (28 waves/CU).
template <int MODE>
__global__ __launch_bounds__(256, 7) void k_edge_conv(
    const int* __restrict__ srcP,
    const float* __restrict__ scaleP, const float* __restrict__ distP,
    const float* __restrict__ xsum, const float* __restrict__ x,
    const float* __restrict__ W1, const float* __restrict__ B1,
    const float* __restrict__ B2,
    const uint4* __restrict__ WF,
    unsigned* __restrict__ kvB, int E)
{
  __shared__ unsigned smem[4 * 1344];
  int tid = threadIdx.x;
  int w = __builtin_amdgcn_readfirstlane(tid >> 6);
  int l = tid & 63;
  int quad = l >> 4;
  int lo = l & 15;
  unsigned* WS  = smem + w * 1344;     // per-wave private region (5376 B)
  unsigned* P   = WS;                  // [0,1024)    quarter-P (swizzled), aliases:
  float*    xsS = (float*)WS;          //   [0,320)   16 x 20 f32 x[src]
  unsigned* xsB = WS + 320;            //   [320,512) 16 x 12 (8 used) bf16 pairs x
  unsigned* efB = WS + 512;            //   [512,704) 16 x 12 bf16 pairs ef
  unsigned* h1P = WS + 704;            //   [704,1024) 16 x 20 (16 used) pairs (m,m+16)
  unsigned* h2P = WS + 1024;           // [1024,1344) 16 x 20 pairs / f32 kv stage

  int ebw = blockIdx.x * 64 + w * 16;

  // ---- early independent global loads (off the critical chain) ----
  float b2a = B2[lo], b2b = B2[16 + lo];
  float scv[4];
#pragma unroll
  for (int r = 0; r < 4; r++) scv[r] = scaleP[ebw + quad * 4 + r];

  // ---- gather (4 lanes per edge, wave-local) ----
  {
    int e4 = l >> 2, c4 = l & 3;
    int s4 = srcP[ebw + e4];
    float4 xv4 = ((const float4*)(x + (size_t)s4 * 16))[c4];
    float4 ev4;
    if (MODE == 2) {
      ev4 = ((const float4*)(xsum + (size_t)s4 * 16))[c4];
      if (c4 == 3) ev4.w += distP[ebw + e4];
    }
    *(float4*)&xsS[e4 * 20 + c4 * 4] = xv4;
    uint2 xp; xp.x = pk2(xv4.x, xv4.y); xp.y = pk2(xv4.z, xv4.w);
    *(uint2*)&xsB[e4 * 12 + c4 * 2] = xp;
    if (MODE == 2) {
      uint2 ep; ep.x = pk2(ev4.x, ev4.y); ep.y = pk2(ev4.z, ev4.w);
      *(uint2*)&efB[e4 * 12 + c4 * 2] = ep;
    }
  }

  // ---- h1 -> h1P as bf16 pairs: dword d of row e holds (m=d, m=d+16) ----
  if (MODE == 0) {
    float dd = distP[ebw + lo];
#pragma unroll
    for (int jj = 0; jj < 4; jj++) {
      int d = quad * 4 + jj;
      float v0 = fmaxf(B1[d]      + dd * W1[15 * 32 + d],      0.f);
      float v1 = fmaxf(B1[d + 16] + dd * W1[15 * 32 + d + 16], 0.f);
      h1P[lo * 20 + d] = pk2(v0, v1);
    }
  } else {
    float b1a = B1[lo], b1b = B1[16 + lo];
    FragU a, b0, b1;
    uint4 r = *(const uint4*)&efB[lo * 12 + (quad & 1) * 4];
    uint4 z = make_uint4(0, 0, 0, 0);
    a.u = (quad >= 2) ? z : r;
    b0.u = WF[19 * 64 + l];
    b1.u = WF[20 * 64 + l];
    f32x4 c0 = {0.f, 0.f, 0.f, 0.f};
    f32x4 c1 = {0.f, 0.f, 0.f, 0.f};
    c0 = __builtin_amdgcn_mfma_f32_16x16x32_bf16(a.s, b0.s, c0, 0, 0, 0);
    c1 = __builtin_amdgcn_mfma_f32_16x16x32_bf16(a.s, b1.s, c1, 0, 0, 0);
#pragma unroll
    for (int r2 = 0; r2 < 4; r2++)
      h1P[(quad * 4 + r2) * 20 + lo] =
          pk2(fmaxf(c0[r2] + b1a, 0.f), fmaxf(c1[r2] + b1b, 0.f));
  }

  // ---- h2 via MFMA (W2 prepacked pair-interleaved) -> h2P pairs (m,m+16) ----
  {
    FragU a, b0, b1;
    a.u = *(const uint4*)&h1P[lo * 20 + quad * 4];
    b0.u = WF[17 * 64 + l];
    b1.u = WF[18 * 64 + l];
    f32x4 hc0 = {0.f, 0.f, 0.f, 0.f};
    f32x4 hc1 = {0.f, 0.f, 0.f, 0.f};
    hc0 = __builtin_amdgcn_mfma_f32_16x16x32_bf16(a.s, b0.s, hc0, 0, 0, 0);
    hc1 = __builtin_amdgcn_mfma_f32_16x16x32_bf16(a.s, b1.s, hc1, 0, 0, 0);
#pragma unroll
    for (int r = 0; r < 4; r++)
      h2P[(quad * 4 + r) * 20 + lo] =
          pk2(fmaxf(hc0[r] + b2a, 0.f), fmaxf(hc1[r] + b2b, 0.f));
  }

  // ---- pull P-build operands into registers (frees the staging region) ----
  float2v xs2[8];
  {
    const float4* xr = (const float4*)&xsS[lo * 20];   // broadcast reads
#pragma unroll
    for (int i = 0; i < 4; i++) {
      float4 t = xr[i];
      float2v a; a.x = t.x; a.y = t.y;
      float2v b; b.x = t.z; b.y = t.w;
      xs2[2 * i]     = a;
      xs2[2 * i + 1] = b;
    }
  }
  uint2 hA = *(const uint2*)&h2P[lo * 20 + quad * 2];      // m = 2q..2q+1 (+16 hi)
  uint2 hB = *(const uint2*)&h2P[lo * 20 + 8 + quad * 2];  // m = 8+2q..  (+16 hi)
  float hmv[8];
  hmv[0] = xbf(hA.x, 0); hmv[1] = xbf(hA.y, 0);   // quarter 0: m in [0,8)
  hmv[2] = xbf(hB.x, 0); hmv[3] = xbf(hB.y, 0);   // quarter 1: m in [8,16)
  hmv[4] = xbf(hA.x, 1); hmv[5] = xbf(hA.y, 1);   // quarter 2: m in [16,24)
  hmv[6] = xbf(hB.x, 1); hmv[7] = xbf(hB.y, 1);   // quarter 3: m in [24,32)

  // ---- bias term: kv += x @ B3 (reads xsB before P overwrites it) ----
  f32x4 acc = {0.f, 0.f, 0.f, 0.f};
  {
    FragU a, b;
    uint4 r = *(const uint4*)&xsB[lo * 12 + (quad & 1) * 4];
    uint4 z = make_uint4(0, 0, 0, 0);
    a.u = (quad >= 2) ? z : r;
    b.u = WF[16 * 64 + l];
    acc = __builtin_amdgcn_mfma_f32_16x16x32_bf16(a.s, b.s, acc, 0, 0, 0);
  }

  // ---- 4 quarter-phases: build 2 m-rows of P per lane, 4 MFMAs per phase ----
#pragma unroll
  for (int q = 0; q < 4; q++) {
#pragma unroll
    for (int j = 0; j < 2; j++) {
      float hm = hmv[q * 2 + j];
      float2v hm2; hm2.x = hm; hm2.y = hm;
      uint4 d0, d1;
      float2v p0 = pkmul2(hm2, xs2[0]);
      float2v p1 = pkmul2(hm2, xs2[1]);
      float2v p2 = pkmul2(hm2, xs2[2]);
      float2v p3 = pkmul2(hm2, xs2[3]);
      d0.x = pk2(p0.x, p0.y); d0.y = pk2(p1.x, p1.y);
      d0.z = pk2(p2.x, p2.y); d0.w = pk2(p3.x, p3.y);
      float2v p4 = pkmul2(hm2, xs2[4]);
      float2v p5 = pkmul2(hm2, xs2[5]);
      float2v p6 = pkmul2(hm2, xs2[6]);
      float2v p7 = pkmul2(hm2, xs2[7]);
      d1.x = pk2(p4.x, p4.y); d1.y = pk2(p5.x, p5.y);
      d1.z = pk2(p6.x, p6.y); d1.w = pk2(p7.x, p7.y);
      int cb = quad * 4 + j * 2;                 // chunk base (m_local*2)
      *(uint4*)&P[lo * 64 + (((cb)     ^ lo) << 2)] = d0;
      *(uint4*)&P[lo * 64 + (((cb + 1) ^ lo) << 2)] = d1;
    }
#pragma unroll
    for (int t = 0; t < 4; t++) {
      FragU a, b;
      a.u = *(const uint4*)&P[lo * 64 + (((t * 4 + quad) ^ lo) << 2)];
      b.u = WF[(q * 4 + t) * 64 + l];
      acc = __builtin_amdgcn_mfma_f32_16x16x32_bf16(a.s, b.s, acc, 0, 0, 0);
    }
  }

  // ---- kv epilogue: scale, stage f32 (reuse h2P), pack, coalesced store ----
#pragma unroll
  for (int r = 0; r < 4; r++) {
    int e = quad * 4 + r;
    ((float*)h2P)[e * 20 + lo] = acc[r] * (F_Y0 * scv[r]);
  }
  {
    int e2 = l >> 2, c = l & 3;
    const float* row = (const float*)&h2P[e2 * 20 + c * 4];
    float4 t = *(const float4*)row;
    uint2 pkd;
    pkd.x = pk2(t.x, t.y);
    pkd.y = pk2(t.z, t.w);
    *(uint2*)(kvB + ((size_t)(ebw + e2) * 8 + c * 2)) = pkd;
  }
}

// ---------------- fused softmax-gather + node update: ONE WAVE PER NODE ----
// lane = (head h, edge-slot s in [0,8)); 8 edge rows (256B contiguous) in
// flight per iteration; shfl_xor reduction over s; projection + q-next on
// lanes<16 with wave-local LDS (no __syncthreads).
template <bool INIT>
__global__ __launch_bounds__(256) void k_agg_update(
    const int* __restrict__ row_ptr, const float* __restrict__ scaleP,
    const unsigned* __restrict__ kvB, const float* __restrict__ qin,
    const float* __restrict__ xin,
    const float* __restrict__ Wproj, const float* __restrict__ Wq_next,
    float* __restrict__ xout, float* __restrict__ qout, float* __restrict__ xsum, int N)
{
  __shared__ float sA[4 * 8];
  __shared__ float sX[4 * 16];
  __shared__ float sN[4 * 16];
  int tid = threadIdx.x;
  int w = __builtin_amdgcn_readfirstlane(tid >> 6);
  int l = tid & 63;
  int h = l & 7;
  int s = l >> 3;
  int t16 = l & 15;
  int n = blockIdx.x * 4 + w;
  int hd = h >> 1, hh = h & 1;

  if (l < 16) sX[w * 16 + t16] = xin[(size_t)n * 16 + t16];

  float qh = qin[(size_t)n * 8 + h];
  int j0 = row_ptr[n], j1 = row_ptr[n + 1];
  float num = 0.f, den = 0.f;
  for (int j = j0 + s; j < j1; j += 8) {
    float val = xbf(kvB[(size_t)j * 8 + hd], hh);
    float key = xbf(kvB[(size_t)j * 8 + 4 + hd], hh);
    float lg = fminf(key * qh, 60.0f);
    float wv = scaleP[j] * __expf(lg);
    num += wv * val;
    den += wv;
  }
  num += __shfl_xor(num, 8, 64);  den += __shfl_xor(den, 8, 64);
  num += __shfl_xor(num, 16, 64); den += __shfl_xor(den, 16, 64);
  num += __shfl_xor(num, 32, 64); den += __shfl_xor(den, 32, 64);
  if (l < 8) sA[w * 8 + h] = num / fmaxf(den, 1e-20f);

  if (l < 16) {
    float cat[24];
#pragma unroll
    for (int j = 0; j < 8; j++) cat[j] = sA[w * 8 + j];
#pragma unroll
    for (int j = 0; j < 16; j++) cat[8 + j] = sX[w * 16 + j];
    float xn = 0.f;
#pragma unroll
    for (int j = 0; j < 24; j++) xn += Wproj[t16 * 24 + j] * cat[j];
    xout[(size_t)n * 16 + t16] = xn;
    if (INIT) {
      xsum[(size_t)n * 16 + t16] = xn;
    } else {
      xsum[(size_t)n * 16 + t16] += xn;
    }
    sN[w * 16 + t16] = xn;
  }
  if (l < 8) {
    float a = 0.f;
#pragma unroll
    for (int i = 0; i < 16; i++) a += Wq_next[h * 16 + i] * sN[w * 16 + i];
    qout[(size_t)n * 8 + h] = a;
  }
}

// ---------------- fused feats gather + final MLP: ONE WAVE PER NODE ----------
__global__ __launch_bounds__(256) void k_feats_final(
    const int* __restrict__ row_ptr, const unsigned* __restrict__ kvB,
    const float* __restrict__ x,
    const int* __restrict__ species, const float* __restrict__ emb,
    const float* __restrict__ Wself,
    const float* __restrict__ mW1, const float* __restrict__ mb1,
    const float* __restrict__ mW2, const float* __restrict__ mb2,
    const float* __restrict__ mW3, const float* __restrict__ mb3,
    float* __restrict__ learn_part, int N)
{
  __shared__ float sX[4 * 16];
  __shared__ float sC[4 * 32];
  __shared__ float sH[4 * 16];
  int tid = threadIdx.x;
  int w = __builtin_amdgcn_readfirstlane(tid >> 6);
  int l = tid & 63;
  int o = l & 15;
  int s = l >> 4;
  int n = blockIdx.x * 4 + w;
  int od = o >> 1, oh = o & 1;

  if (l < 4) {
    float4 v = ((const float4*)(x + (size_t)n * 16))[l];
    *(float4*)&sX[w * 16 + l * 4] = v;
  } else if (l < 8) {
    int sp = species[n] - 1;
    float4 v = ((const float4*)(emb + (size_t)sp * 16))[l - 4];
    *(float4*)&sC[w * 32 + (l - 4) * 4] = v;
  }

  int j0 = row_ptr[n], j1 = row_ptr[n + 1];
  float ft = 0.f;
  for (int j = j0 + s; j < j1; j += 4) ft += xbf(kvB[(size_t)j * 8 + od], oh);
  ft += __shfl_xor(ft, 16, 64);
  ft += __shfl_xor(ft, 32, 64);

  float contrib = 0.f;
  if (l < 16) {
    float xv[16];
    load16(&sX[w * 16], xv);
    float a = ft;
#pragma unroll
    for (int i = 0; i < 16; i++) a += Wself[o * 16 + i] * xv[i];
    sC[w * 32 + 16 + o] = a;

    float cat[32];
    load16(&sC[w * 32], cat);
    load16(&sC[w * 32 + 16], cat + 16);
    float h1v = mb1[o];
#pragma unroll
    for (int k = 0; k < 32; k++) h1v += cat[k] * mW1[k * 16 + o];
    h1v = siluf(h1v);
    sH[w * 16 + o] = h1v;

    float hv[16];
    load16(&sH[w * 16], hv);
    float h2v = mb2[o];
#pragma unroll
    for (int k = 0; k < 16; k++) h2v += hv[k] * mW2[k * 16 + o];
    h2v = siluf(h2v);
    contrib = h2v * mW3[o] + ((o == 0) ? mb3[0] : 0.f);
  }
  block_reduce_store(contrib, learn_part);
}

// ---------------- final reduction ----------------
__global__ __launch_bounds__(256) void k_finalize(
    const float* __restrict__ coul_part, int nc,
    const float* __restrict__ learn_part, int nl,
    float* __restrict__ out)
{
  __shared__ float sred[4];
  int tid = threadIdx.x;
  float v = 0.f;
  for (int i = tid; i < nc; i += 256) v += coul_part[i];
  for (int i = tid; i < nl; i += 256) v += learn_part[i];
#pragma unroll
  for (int off = 32; off > 0; off >>= 1) v += __shfl_down(v, off, 64);
  if ((tid & 63) == 0) sred[tid >> 6] = v;
  __syncthreads();
  if (tid == 0) out[0] = sred[0] + sred[1] + sred[2] + sred[3];
}

extern "C" void kernel_launch(void* const* d_in, const int* in_sizes, int n_in,
                              void* d_out, int out_size, void* d_ws, size_t ws_size,
                              hipStream_t stream)
{
  const int*   species = (const int*)d_in[0];
  const int*   src     = (const int*)d_in[1];
  const int*   dst     = (const int*)d_in[2];
  const float* rel_pos = (const float*)d_in[3];
  const float* emb     = (const float*)d_in[4];
  const float* kv_W1   = (const float*)d_in[5];
  const float* kv_b1   = (const float*)d_in[6];
  const float* kv_W2   = (const float*)d_in[7];
  const float* kv_b2   = (const float*)d_in[8];
  const float* kv_W3   = (const float*)d_in[9];
  const float* kv_b3   = (const float*)d_in[10];
  const float* Wq      = (const float*)d_in[11];
  const float* Wproj   = (const float*)d_in[12];
  const float* fin_W1  = (const float*)d_in[13];
  const float* fin_b1  = (const float*)d_in[14];
  const float* fin_W2  = (const float*)d_in[15];
  const float* fin_b2  = (const float*)d_in[16];
  const float* fin_W3  = (const float*)d_in[17];
  const float* fin_b3  = (const float*)d_in[18];
  const float* Wself   = (const float*)d_in[19];
  const float* mlp_W1  = (const float*)d_in[20];
  const float* mlp_b1  = (const float*)d_in[21];
  const float* mlp_W2  = (const float*)d_in[22];
  const float* mlp_b2  = (const float*)d_in[23];
  const float* mlp_W3  = (const float*)d_in[24];
  const float* mlp_b3  = (const float*)d_in[25];

  const int N = in_sizes[0];
  const int E = in_sizes[1];
  const int nblk_e = (E + 255) / 256;
  const int nblk_n = (N + 255) / 256;
  const int nblk_f = N / 4;

  char* p = (char*)d_ws;
  auto alloc = [&](size_t bytes) -> void* {
    void* r = (void*)p;
    p += (bytes + 255) & ~(size_t)255;
    return r;
  };
  float*    dist_   = (float*)alloc((size_t)E * 4);
  float*    scale_  = (float*)alloc((size_t)E * 4);
  float*    distP   = (float*)alloc((size_t)E * 4);
  float*    scaleP  = (float*)alloc((size_t)E * 4);
  int*      srcP    = (int*)  alloc((size_t)E * 4);
  unsigned* kvB     = (unsigned*)alloc((size_t)E * 8 * 4);
  float*    xA      = (float*)alloc((size_t)N * 16 * 4);
  float*    xB      = (float*)alloc((size_t)N * 16 * 4);
  float*    xsum    = (float*)alloc((size_t)N * 16 * 4);
  float*    q       = (float*)alloc((size_t)N * 8 * 4);
  int*      cnt     = (int*)  alloc((size_t)N * 4);
  int*      row_ptr = (int*)  alloc((size_t)(N + 1) * 4);
  int*      row_cur = (int*)  alloc((size_t)N * 4);
  int*      bsum    = (int*)  alloc(128 * 4);
  int*      boff    = (int*)  alloc(128 * 4);
  uint4*    WF      = (uint4*)alloc((size_t)5 * 21 * 64 * 16);
  float*    coul_part  = (float*)alloc((size_t)nblk_e * 4);
  float*    learn_part = (float*)alloc((size_t)nblk_f * 4);

  dim3 blk(256);
  dim3 egrid(nblk_e);
  dim3 cgrid(E / 64);
  dim3 ngrid(nblk_n);
  dim3 augrid(N / 4);
  dim3 fgrid(nblk_f);

  hipMemsetAsync(cnt, 0, (size_t)N * 4, stream);

  k_prepack<<<dim3(27), blk, 0, stream>>>(kv_W3, kv_b3, fin_W3, fin_b3,
                                          kv_W2, fin_W2, kv_W1, fin_W1, WF);

  k_pre<<<egrid, blk, 0, stream>>>(species, src, dst, rel_pos, dist_, scale_,
                                   cnt, coul_part, E);
  k_scan1<<<ngrid, blk, 0, stream>>>(cnt, row_ptr, bsum);
  k_scan2<<<dim3(1), dim3(128), 0, stream>>>(bsum, boff);
  k_scan3<<<ngrid, blk, 0, stream>>>(row_ptr, row_cur, boff, N, E);
  k_scatter_perm<<<egrid, blk, 0, stream>>>(src, dst, dist_, scale_, row_cur,
                                            srcP, distP, scaleP, E);

  k_node_init<<<ngrid, blk, 0, stream>>>(species, emb, Wq, xA, q, N);

  float* xin = xA;
  float* xout = xB;
  for (int l = 0; l < 4; l++) {
    const float* W1 = kv_W1 + (size_t)l * 16 * 32;
    const float* B1 = kv_b1 + (size_t)l * 32;
    const float* B2 = kv_b2 + (size_t)l * 32;
    const uint4* WFl = WF + (size_t)l * 21 * 64;
    const float* Wqn = Wq + (size_t)((l < 3) ? (l + 1) : 0) * 8 * 16;
    if (l == 0) {
      k_edge_conv<0><<<cgrid, blk, 0, stream>>>(srcP, scaleP, distP, xsum, xin,
                                                W1, B1, B2, WFl, kvB, E);
    } else {
      k_edge_conv<2><<<cgrid, blk, 0, stream>>>(srcP, scaleP, distP, xsum, xin,
                                                W1, B1, B2, WFl, kvB, E);
    }
    if (l == 0) {
      k_agg_update<true><<<augrid, blk, 0, stream>>>(row_ptr, scaleP, kvB, q, xin,
                                                     Wproj, Wqn, xout, q, xsum, N);
    } else {
      k_agg_update<false><<<augrid, blk, 0, stream>>>(row_ptr, scaleP, kvB, q, xin,
                                                      Wproj + (size_t)l * 16 * 24, Wqn,
                                                      xout, q, xsum, N);
    }
    float* tmp = xin; xin = xout; xout = tmp;
  }

  k_edge_conv<2><<<cgrid, blk, 0, stream>>>(srcP, scaleP, distP, xsum, xin,
                                            fin_W1, fin_b1, fin_b2,
                                            WF + (size_t)4 * 21 * 64, kvB, E);
  k_feats_final<<<fgrid, blk, 0, stream>>>(row_ptr, kvB, xin, species, emb, Wself,
                                           mlp_W1, mlp_b1, mlp_W2, mlp_b2, mlp_W3, mlp_b3,
                                           learn_part, N);
  k_finalize<<<dim3(1), blk, 0, stream>>>(coul_part, nblk_e, learn_part, nblk_f,
                                          (float*)d_out);
}

// Round 4
// 408.592 us; speedup vs baseline: 1.1203x; 1.1203x over previous
//
#include <hip/hip_runtime.h>

constexpr float F_Y0     = 0.28209479177387814f;
constexpr float F_CUTOFF = 4.6f;

typedef short short8 __attribute__((ext_vector_type(8)));
typedef float f32x4  __attribute__((ext_vector_type(4)));
typedef float float2v __attribute__((ext_vector_type(2)));

__device__ __forceinline__ float siluf(float v) { return v / (1.0f + __expf(-v)); }

// gfx950 hardware packed fp32->bf16 (RNE): lo = cvt(a), hi = cvt(b)
__device__ __forceinline__ unsigned pk2(float a, float b) {
  unsigned r;
  asm("v_cvt_pk_bf16_f32 %0, %1, %2" : "=v"(r) : "v"(a), "v"(b));
  return r;
}
// extract bf16 half h (0=lo,1=hi) of dword d as fp32
__device__ __forceinline__ float xbf(unsigned d, int h) {
  return __uint_as_float(h ? (d & 0xffff0000u) : (d << 16));
}
// packed fp32 multiply (full-rate VOP3P on CDNA)
__device__ __forceinline__ float2v pkmul2(float2v a, float2v b) {
  float2v d;
  asm("v_pk_mul_f32 %0, %1, %2" : "=v"(d) : "v"(a), "v"(b));
  return d;
}

union FragU { uint4 u; short8 s; };

__device__ __forceinline__ void load16(const float* p, float* r) {
  const float4* p4 = (const float4*)p;
#pragma unroll
  for (int i = 0; i < 4; i++) {
    float4 t = p4[i];
    r[4*i] = t.x; r[4*i+1] = t.y; r[4*i+2] = t.z; r[4*i+3] = t.w;
  }
}
__device__ __forceinline__ void store16(float* p, const float* r) {
  float4* p4 = (float4*)p;
#pragma unroll
  for (int i = 0; i < 4; i++) p4[i] = make_float4(r[4*i], r[4*i+1], r[4*i+2], r[4*i+3]);
}

// block-level sum of one float per thread -> part[blockIdx.x]
__device__ __forceinline__ void block_reduce_store(float v, float* part) {
  __shared__ float sred[4];
  int tid = threadIdx.x;
#pragma unroll
  for (int off = 32; off > 0; off >>= 1) v += __shfl_down(v, off, 64);
  if ((tid & 63) == 0) sred[tid >> 6] = v;
  __syncthreads();
  if (tid == 0) part[blockIdx.x] = sred[0] + sred[1] + sred[2] + sred[3];
}

// ---------------- per-edge precompute (+ CSR histogram fused) ----------------
// Z^0.23 via per-block LDS table (species in [1,90)) instead of 2 powf/edge.
__global__ __launch_bounds__(256) void k_pre(
    const int* __restrict__ species, const int* __restrict__ src, const int* __restrict__ dst,
    const float* __restrict__ rel_pos,
    float* __restrict__ dist_, float* __restrict__ scale_,
    int* __restrict__ cnt,
    float* __restrict__ coul_part, int E)
{
  __shared__ float zpow[128];
  int tid = threadIdx.x;
  if (tid < 128) zpow[tid] = __powf((float)tid, 0.23f);
  __syncthreads();

  int e = blockIdx.x * 256 + tid;
  float ce = 0.0f;
  if (e < E) {
    float px = rel_pos[3*(size_t)e + 0];
    float py = rel_pos[3*(size_t)e + 1];
    float pz = rel_pos[3*(size_t)e + 2];
    float dist = sqrtf(px*px + py*py + pz*pz);
    float xc = dist * (1.0f / F_CUTOFF);
    bool in_cut = dist < F_CUTOFF;
    float x2 = in_cut ? xc * xc : 0.0f;
    x2 = fminf(x2, 1.0f - 1e-6f);
    float sc = in_cut ? __expf(3.0f - 3.0f / (1.0f - x2)) : 0.0f;
    dist_[e] = dist;
    scale_[e] = sc;
    atomicAdd(&cnt[dst[e]], 1);
    int spu = species[src[e]], spv = species[dst[e]];
    float Zu = (float)spu;
    float Zv = (float)spv;
    float raw = 0.529f * Zu * Zv / (2.0f * dist);
    float au = 0.8854f * 0.529f / (zpow[spu] + zpow[spv]);
    float xx = dist / au;
    float screen = 0.1818f   * __expf(-3.2f    * xx)
                 + 0.5099f   * __expf(-0.9423f * xx)
                 + 0.2802f   * __expf(-0.4028f * xx)
                 + 0.02817f  * __expf(-0.2016f * xx);
    ce = raw * screen * sc;
  }
  block_reduce_store(ce, coul_part);
}

// ---------------- CSR scans ----------------
__global__ __launch_bounds__(256) void k_scan1(
    const int* __restrict__ cnt, int* __restrict__ row_ptr, int* __restrict__ bsum)
{
  __shared__ int s[256];
  int tid = threadIdx.x;
  int n = blockIdx.x * 256 + tid;
  int v = cnt[n];
  s[tid] = v;
  __syncthreads();
#pragma unroll
  for (int off = 1; off < 256; off <<= 1) {
    int t = (tid >= off) ? s[tid - off] : 0;
    __syncthreads();
    s[tid] += t;
    __syncthreads();
  }
  row_ptr[n] = s[tid] - v;
  if (tid == 255) bsum[blockIdx.x] = s[255];
}

__global__ __launch_bounds__(128) void k_scan2(int* __restrict__ bsum, int* __restrict__ boff)
{
  __shared__ int s[128];
  int tid = threadIdx.x;
  int v = bsum[tid];
  s[tid] = v;
  __syncthreads();
#pragma unroll
  for (int off = 1; off < 128; off <<= 1) {
    int t = (tid >= off) ? s[tid - off] : 0;
    __syncthreads();
    s[tid] += t;
    __syncthreads();
  }
  boff[tid] = s[tid] - v;
}

__global__ __launch_bounds__(256) void k_scan3(
    int* __restrict__ row_ptr, int* __restrict__ row_cur,
    const int* __restrict__ boff, int N, int E)
{
  int n = blockIdx.x * 256 + threadIdx.x;
  int rp = row_ptr[n] + boff[blockIdx.x];
  row_ptr[n] = rp;
  row_cur[n] = rp;
  if (n == 0) row_ptr[N] = E;
}

__global__ __launch_bounds__(256) void k_scatter_perm(
    const int* __restrict__ dst, int* __restrict__ row_cur,
    int* __restrict__ perm, int E)
{
  int e = blockIdx.x * 256 + threadIdx.x;
  if (e >= E) return;
  int pos = atomicAdd(&row_cur[dst[e]], 1);
  perm[pos] = e;
}

__global__ __launch_bounds__(256) void k_permute(
    const int* __restrict__ perm,
    const int* __restrict__ src, const float* __restrict__ dist_, const float* __restrict__ scale_,
    int* __restrict__ srcP, float* __restrict__ distP, float* __restrict__ scaleP, int E)
{
  int i = blockIdx.x * 256 + threadIdx.x;
  if (i >= E) return;
  int e = perm[i];
  srcP[i]   = src[e];
  distP[i]  = dist_[e];
  scaleP[i] = scale_[e];
}

// ---------------- weight prepack: per layer 21 bf16 B-fragments ----------------
// NOTE: W2 fragments (f=17,18) are k-interleaved to match the pair layout
// (m, m+16) that h1 is stored in: physical k position p holds logical
// row m(p) = (p&1) ? 16+(p>>1) : (p>>1).
__global__ __launch_bounds__(256) void k_prepack(
    const float* __restrict__ kv_W3, const float* __restrict__ kv_b3,
    const float* __restrict__ fin_W3, const float* __restrict__ fin_b3,
    const float* __restrict__ kv_W2, const float* __restrict__ fin_W2,
    const float* __restrict__ kv_W1, const float* __restrict__ fin_W1,
    uint4* __restrict__ WF)
{
  int t = blockIdx.x * 256 + threadIdx.x;
  if (t >= 5 * 21 * 64) return;
  int lyr = t / (21 * 64);
  int rem = t - lyr * 21 * 64;
  int f = rem >> 6;
  int l = rem & 63;
  int qq = l >> 4;
  int o = l & 15;
  const float* W3 = (lyr < 4) ? (kv_W3 + (size_t)lyr * 32 * 256) : fin_W3;
  const float* B3 = (lyr < 4) ? (kv_b3 + (size_t)lyr * 256) : fin_b3;
  const float* W2 = (lyr < 4) ? (kv_W2 + (size_t)lyr * 32 * 32) : fin_W2;
  const float* W1 = (lyr < 4) ? (kv_W1 + (size_t)lyr * 16 * 32) : fin_W1;
  float v[8];
#pragma unroll
  for (int j = 0; j < 8; j++) {
    if (f < 16) {
      int kk = f * 32 + qq * 8 + j;
      int m = kk >> 4, i = kk & 15;
      v[j] = W3[m * 256 + o * 16 + i];
    } else if (f == 16) {
      int r = qq * 8 + j;
      int mp = r >> 4, i = r & 15;
      v[j] = mp ? 0.0f : B3[o * 16 + i];
    } else if (f < 19) {
      int c = f - 17;
      int p = qq * 8 + j;                       // physical k position
      int m = (p & 1) ? (16 + (p >> 1)) : (p >> 1);  // pair-interleave
      v[j] = W2[m * 32 + c * 16 + o];
    } else {
      int c = f - 19;
      int k = qq * 8 + j;
      v[j] = (k < 16) ? W1[k * 32 + c * 16 + o] : 0.0f;
    }
  }
  uint4 dw;
  dw.x = pk2(v[0], v[1]);
  dw.y = pk2(v[2], v[3]);
  dw.z = pk2(v[4], v[5]);
  dw.w = pk2(v[6], v[7]);
  WF[t] = dw;
}

// ---------------- node init (x, q0; semb read on-demand later) ----------------
__global__ __launch_bounds__(256) void k_node_init(
    const int* __restrict__ species, const float* __restrict__ emb,
    const float* __restrict__ Wq0,
    float* __restrict__ x, float* __restrict__ q, int N)
{
  int n = blockIdx.x * 256 + threadIdx.x;
  if (n >= N) return;
  int sp = species[n] - 1;
  float xv[16];
  load16(emb + (size_t)sp * 16, xv);
  store16(x + (size_t)n * 16, xv);
  float qv[8];
#pragma unroll
  for (int h = 0; h < 8; h++) {
    float a = 0.f;
#pragma unroll
    for (int i = 0; i < 16; i++) a += Wq0[h * 16 + i] * xv[i];
    qv[h] = a;
  }
  float4* qp = (float4*)(q + (size_t)n * 8);
  qp[0] = make_float4(qv[0], qv[1], qv[2], qv[3]);
  qp[1] = make_float4(qv[4], qv[5], qv[6], qv[7]);
}

// ---------------- heavy edge conv: WAVE-LOCAL, zero __syncthreads ----------
// Each wave owns 16 edges end-to-end in a wave-private LDS region.
// LDS aliasing: P [0,1024) overlays the staging buffers {xsS,xsB,efB,h1P},
// which are all dead before the first P write (consumed by the h1/h2 MFMAs
// or pulled into registers: xs2, bias A-frag, hmv). Same-wave DS ops are
// processed in issue order and every P-write's data has a true register
// dependency on those reads, so the WAR overlap is safe.
// Per-wave: 1344 dw = 5376 B; block = 21504 B -> 7 blocks/CU (28 waves/CU).
template <int MODE>
__global__ __launch_bounds__(256, 7) void k_edge_conv(
    const int* __restrict__ srcP,
    const float* __restrict__ scaleP, const float* __restrict__ distP,
    const float* __restrict__ xsum, const float* __restrict__ x,
    const float* __restrict__ W1, const float* __restrict__ B1,
    const float* __restrict__ B2,
    const uint4* __restrict__ WF,
    unsigned* __restrict__ kvB, int E)
{
  __shared__ unsigned smem[4 * 1344];
  int tid = threadIdx.x;
  int w = __builtin_amdgcn_readfirstlane(tid >> 6);
  int l = tid & 63;
  int quad = l >> 4;
  int lo = l & 15;
  unsigned* WS  = smem + w * 1344;     // per-wave private region (5376 B)
  unsigned* P   = WS;                  // [0,1024)    quarter-P (swizzled), aliases:
  float*    xsS = (float*)WS;          //   [0,320)   16 x 20 f32 x[src]
  unsigned* xsB = WS + 320;            //   [320,512) 16 x 12 (8 used) bf16 pairs x
  unsigned* efB = WS + 512;            //   [512,704) 16 x 12 bf16 pairs ef
  unsigned* h1P = WS + 704;            //   [704,1024) 16 x 20 (16 used) pairs (m,m+16)
  unsigned* h2P = WS + 1024;           // [1024,1344) 16 x 20 pairs / f32 kv stage

  int ebw = blockIdx.x * 64 + w * 16;

  // ---- early independent global loads (off the critical chain) ----
  float b2a = B2[lo], b2b = B2[16 + lo];
  float scv[4];
#pragma unroll
  for (int r = 0; r < 4; r++) scv[r] = scaleP[ebw + quad * 4 + r];

  // ---- gather (4 lanes per edge, wave-local) ----
  {
    int e4 = l >> 2, c4 = l & 3;
    int s4 = srcP[ebw + e4];
    float4 xv4 = ((const float4*)(x + (size_t)s4 * 16))[c4];
    float4 ev4;
    if (MODE == 2) {
      ev4 = ((const float4*)(xsum + (size_t)s4 * 16))[c4];
      if (c4 == 3) ev4.w += distP[ebw + e4];
    }
    *(float4*)&xsS[e4 * 20 + c4 * 4] = xv4;
    uint2 xp; xp.x = pk2(xv4.x, xv4.y); xp.y = pk2(xv4.z, xv4.w);
    *(uint2*)&xsB[e4 * 12 + c4 * 2] = xp;
    if (MODE == 2) {
      uint2 ep; ep.x = pk2(ev4.x, ev4.y); ep.y = pk2(ev4.z, ev4.w);
      *(uint2*)&efB[e4 * 12 + c4 * 2] = ep;
    }
  }

  // ---- h1 -> h1P as bf16 pairs: dword d of row e holds (m=d, m=d+16) ----
  if (MODE == 0) {
    float dd = distP[ebw + lo];
#pragma unroll
    for (int jj = 0; jj < 4; jj++) {
      int d = quad * 4 + jj;
      float v0 = fmaxf(B1[d]      + dd * W1[15 * 32 + d],      0.f);
      float v1 = fmaxf(B1[d + 16] + dd * W1[15 * 32 + d + 16], 0.f);
      h1P[lo * 20 + d] = pk2(v0, v1);
    }
  } else {
    float b1a = B1[lo], b1b = B1[16 + lo];
    FragU a, b0, b1;
    uint4 r = *(const uint4*)&efB[lo * 12 + (quad & 1) * 4];
    uint4 z = make_uint4(0, 0, 0, 0);
    a.u = (quad >= 2) ? z : r;
    b0.u = WF[19 * 64 + l];
    b1.u = WF[20 * 64 + l];
    f32x4 c0 = {0.f, 0.f, 0.f, 0.f};
    f32x4 c1 = {0.f, 0.f, 0.f, 0.f};
    c0 = __builtin_amdgcn_mfma_f32_16x16x32_bf16(a.s, b0.s, c0, 0, 0, 0);
    c1 = __builtin_amdgcn_mfma_f32_16x16x32_bf16(a.s, b1.s, c1, 0, 0, 0);
#pragma unroll
    for (int r2 = 0; r2 < 4; r2++)
      h1P[(quad * 4 + r2) * 20 + lo] =
          pk2(fmaxf(c0[r2] + b1a, 0.f), fmaxf(c1[r2] + b1b, 0.f));
  }

  // ---- h2 via MFMA (W2 prepacked pair-interleaved) -> h2P pairs (m,m+16) ----
  {
    FragU a, b0, b1;
    a.u = *(const uint4*)&h1P[lo * 20 + quad * 4];
    b0.u = WF[17 * 64 + l];
    b1.u = WF[18 * 64 + l];
    f32x4 hc0 = {0.f, 0.f, 0.f, 0.f};
    f32x4 hc1 = {0.f, 0.f, 0.f, 0.f};
    hc0 = __builtin_amdgcn_mfma_f32_16x16x32_bf16(a.s, b0.s, hc0, 0, 0, 0);
    hc1 = __builtin_amdgcn_mfma_f32_16x16x32_bf16(a.s, b1.s, hc1, 0, 0, 0);
#pragma unroll
    for (int r = 0; r < 4; r++)
      h2P[(quad * 4 + r) * 20 + lo] =
          pk2(fmaxf(hc0[r] + b2a, 0.f), fmaxf(hc1[r] + b2b, 0.f));
  }

  // ---- pull P-build operands into registers (frees the staging region) ----
  float2v xs2[8];
  {
    const float4* xr = (const float4*)&xsS[lo * 20];   // broadcast reads
#pragma unroll
    for (int i = 0; i < 4; i++) {
      float4 t = xr[i];
      float2v a; a.x = t.x; a.y = t.y;
      float2v b; b.x = t.z; b.y = t.w;
      xs2[2 * i]     = a;
      xs2[2 * i + 1] = b;
    }
  }
  uint2 hA = *(const uint2*)&h2P[lo * 20 + quad * 2];      // m = 2q..2q+1 (+16 hi)
  uint2 hB = *(const uint2*)&h2P[lo * 20 + 8 + quad * 2];  // m = 8+2q..  (+16 hi)
  float hmv[8];
  hmv[0] = xbf(hA.x, 0); hmv[1] = xbf(hA.y, 0);   // quarter 0: m in [0,8)
  hmv[2] = xbf(hB.x, 0); hmv[3] = xbf(hB.y, 0);   // quarter 1: m in [8,16)
  hmv[4] = xbf(hA.x, 1); hmv[5] = xbf(hA.y, 1);   // quarter 2: m in [16,24)
  hmv[6] = xbf(hB.x, 1); hmv[7] = xbf(hB.y, 1);   // quarter 3: m in [24,32)

  // ---- bias term: kv += x @ B3 (reads xsB before P overwrites it) ----
  f32x4 acc = {0.f, 0.f, 0.f, 0.f};
  {
    FragU a, b;
    uint4 r = *(const uint4*)&xsB[lo * 12 + (quad & 1) * 4];
    uint4 z = make_uint4(0, 0, 0, 0);
    a.u = (quad >= 2) ? z : r;
    b.u = WF[16 * 64 + l];
    acc = __builtin_amdgcn_mfma_f32_16x16x32_bf16(a.s, b.s, acc, 0, 0, 0);
  }

  // ---- 4 quarter-phases: build 2 m-rows of P per lane, 4 MFMAs per phase ----
#pragma unroll
  for (int q = 0; q < 4; q++) {
#pragma unroll
    for (int j = 0; j < 2; j++) {
      float hm = hmv[q * 2 + j];
      float2v hm2; hm2.x = hm; hm2.y = hm;
      uint4 d0, d1;
      float2v p0 = pkmul2(hm2, xs2[0]);
      float2v p1 = pkmul2(hm2, xs2[1]);
      float2v p2 = pkmul2(hm2, xs2[2]);
      float2v p3 = pkmul2(hm2, xs2[3]);
      d0.x = pk2(p0.x, p0.y); d0.y = pk2(p1.x, p1.y);
      d0.z = pk2(p2.x, p2.y); d0.w = pk2(p3.x, p3.y);
      float2v p4 = pkmul2(hm2, xs2[4]);
      float2v p5 = pkmul2(hm2, xs2[5]);
      float2v p6 = pkmul2(hm2, xs2[6]);
      float2v p7 = pkmul2(hm2, xs2[7]);
      d1.x = pk2(p4.x, p4.y); d1.y = pk2(p5.x, p5.y);
      d1.z = pk2(p6.x, p6.y); d1.w = pk2(p7.x, p7.y);
      int cb = quad * 4 + j * 2;                 // chunk base (m_local*2)
      *(uint4*)&P[lo * 64 + (((cb)     ^ lo) << 2)] = d0;
      *(uint4*)&P[lo * 64 + (((cb + 1) ^ lo) << 2)] = d1;
    }
#pragma unroll
    for (int t = 0; t < 4; t++) {
      FragU a, b;
      a.u = *(const uint4*)&P[lo * 64 + (((t * 4 + quad) ^ lo) << 2)];
      b.u = WF[(q * 4 + t) * 64 + l];
      acc = __builtin_amdgcn_mfma_f32_16x16x32_bf16(a.s, b.s, acc, 0, 0, 0);
    }
  }

  // ---- kv epilogue: scale, stage f32 (reuse h2P), pack, coalesced store ----
#pragma unroll
  for (int r = 0; r < 4; r++) {
    int e = quad * 4 + r;
    ((float*)h2P)[e * 20 + lo] = acc[r] * (F_Y0 * scv[r]);
  }
  {
    int e2 = l >> 2, c = l & 3;
    const float* row = (const float*)&h2P[e2 * 20 + c * 4];
    float4 t = *(const float4*)row;
    uint2 pkd;
    pkd.x = pk2(t.x, t.y);
    pkd.y = pk2(t.z, t.w);
    *(uint2*)(kvB + ((size_t)(ebw + e2) * 8 + c * 2)) = pkd;
  }
}

// ---------------- fused softmax-gather + node update (16 threads/node) ------
// Degree loop software-pipelined 4-deep: 12 independent loads issue before
// the first exp consumes them (serial L2 round-trips 8 -> ~2).
template <bool INIT>
__global__ __launch_bounds__(256) void k_agg_update(
    const int* __restrict__ row_ptr, const float* __restrict__ scaleP,
    const unsigned* __restrict__ kvB, const float* __restrict__ qin,
    const float* __restrict__ xin,
    const float* __restrict__ Wproj, const float* __restrict__ Wq_next,
    float* __restrict__ xout, float* __restrict__ qout, float* __restrict__ xsum, int N)
{
  __shared__ float sA[16 * 8];
  __shared__ float sX[16 * 17];
  __shared__ float sN[16 * 17];
  int tid = threadIdx.x;
  int nl = tid >> 4;
  int t16 = tid & 15;
  int h = t16 & 7;
  int p = t16 >> 3;
  int n = blockIdx.x * 16 + nl;
  int hd = h >> 1, hh = h & 1;

  float qh = qin[(size_t)n * 8 + h];
  int j0 = row_ptr[n], j1 = row_ptr[n + 1];
  float num = 0.f, den = 0.f;
  int j = j0 + p;
  for (; j + 6 < j1; j += 8) {
    unsigned va = kvB[(size_t)j * 8 + hd];
    unsigned ka = kvB[(size_t)j * 8 + 4 + hd];
    unsigned vb = kvB[(size_t)(j + 2) * 8 + hd];
    unsigned kb = kvB[(size_t)(j + 2) * 8 + 4 + hd];
    unsigned vc = kvB[(size_t)(j + 4) * 8 + hd];
    unsigned kc = kvB[(size_t)(j + 4) * 8 + 4 + hd];
    unsigned vd = kvB[(size_t)(j + 6) * 8 + hd];
    unsigned kd = kvB[(size_t)(j + 6) * 8 + 4 + hd];
    float sa = scaleP[j];
    float sb = scaleP[j + 2];
    float sc = scaleP[j + 4];
    float sd = scaleP[j + 6];
    float wa = sa * __expf(fminf(xbf(ka, hh) * qh, 60.0f));
    float wb = sb * __expf(fminf(xbf(kb, hh) * qh, 60.0f));
    float wc = sc * __expf(fminf(xbf(kc, hh) * qh, 60.0f));
    float wd = sd * __expf(fminf(xbf(kd, hh) * qh, 60.0f));
    num += wa * xbf(va, hh) + wb * xbf(vb, hh) + wc * xbf(vc, hh) + wd * xbf(vd, hh);
    den += (wa + wb) + (wc + wd);
  }
  for (; j < j1; j += 2) {
    float val = xbf(kvB[(size_t)j * 8 + hd], hh);
    float key = xbf(kvB[(size_t)j * 8 + 4 + hd], hh);
    float lg = fminf(key * qh, 60.0f);
    float wv = scaleP[j] * __expf(lg);
    num += wv * val;
    den += wv;
  }
  num += __shfl_xor(num, 8, 64);
  den += __shfl_xor(den, 8, 64);
  if (p == 0) sA[nl * 8 + h] = num / fmaxf(den, 1e-20f);
  sX[nl * 17 + t16] = xin[(size_t)n * 16 + t16];
  __syncthreads();

  float cat[24];
#pragma unroll
  for (int jj = 0; jj < 8; jj++) cat[jj] = sA[nl * 8 + jj];
#pragma unroll
  for (int jj = 0; jj < 16; jj++) cat[8 + jj] = sX[nl * 17 + jj];
  float xn = 0.f;
#pragma unroll
  for (int jj = 0; jj < 24; jj++) xn += Wproj[t16 * 24 + jj] * cat[jj];
  xout[(size_t)n * 16 + t16] = xn;
  if (INIT) {
    xsum[(size_t)n * 16 + t16] = xn;
  } else {
    xsum[(size_t)n * 16 + t16] += xn;
  }
  sN[nl * 17 + t16] = xn;
  __syncthreads();

  if (p == 0) {
    float a = 0.f;
#pragma unroll
    for (int i = 0; i < 16; i++) a += Wq_next[h * 16 + i] * sN[nl * 17 + i];
    qout[(size_t)n * 8 + h] = a;
  }
}

// ---------------- fused feats gather + final MLP (16 threads/node) ----------
// Gather loop batched 4-deep for load ILP (serial round-trips 16 -> 4).
__global__ __launch_bounds__(256) void k_feats_final(
    const int* __restrict__ row_ptr, const unsigned* __restrict__ kvB,
    const float* __restrict__ x,
    const int* __restrict__ species, const float* __restrict__ emb,
    const float* __restrict__ Wself,
    const float* __restrict__ mW1, const float* __restrict__ mb1,
    const float* __restrict__ mW2, const float* __restrict__ mb2,
    const float* __restrict__ mW3, const float* __restrict__ mb3,
    float* __restrict__ learn_part, int N)
{
  __shared__ float sX[16 * 20];
  __shared__ float sC[16 * 40];
  __shared__ float sH[16 * 20];
  int tid = threadIdx.x;
  int nl = tid >> 4;
  int o = tid & 15;
  int n = blockIdx.x * 16 + nl;
  int od = o >> 1, oh = o & 1;

  int j0 = row_ptr[n], j1 = row_ptr[n + 1];
  float ft = 0.f;
  int j = j0;
  for (; j + 3 < j1; j += 4) {
    unsigned a = kvB[(size_t)j * 8 + od];
    unsigned b = kvB[(size_t)(j + 1) * 8 + od];
    unsigned c = kvB[(size_t)(j + 2) * 8 + od];
    unsigned d = kvB[(size_t)(j + 3) * 8 + od];
    ft += (xbf(a, oh) + xbf(b, oh)) + (xbf(c, oh) + xbf(d, oh));
  }
  for (; j < j1; ++j) ft += xbf(kvB[(size_t)j * 8 + od], oh);

  if (o < 4) {
    float4 v = ((const float4*)(x + (size_t)n * 16))[o];
    *(float4*)&sX[nl * 20 + o * 4] = v;
  } else if (o < 8) {
    int sp = species[n] - 1;
    float4 v = ((const float4*)(emb + (size_t)sp * 16))[o - 4];
    *(float4*)&sC[nl * 40 + (o - 4) * 4] = v;
  }
  __syncthreads();

  float xv[16];
  load16(&sX[nl * 20], xv);
  float a = ft;
#pragma unroll
  for (int i = 0; i < 16; i++) a += Wself[o * 16 + i] * xv[i];
  sC[nl * 40 + 16 + o] = a;
  __syncthreads();

  float cat[32];
  load16(&sC[nl * 40], cat);
  load16(&sC[nl * 40 + 16], cat + 16);
  float hh = mb1[o];
#pragma unroll
  for (int k = 0; k < 32; k++) hh += cat[k] * mW1[k * 16 + o];
  hh = siluf(hh);
  sH[nl * 20 + o] = hh;
  __syncthreads();

  float hv[16];
  load16(&sH[nl * 20], hv);
  float h2 = mb2[o];
#pragma unroll
  for (int k = 0; k < 16; k++) h2 += hv[k] * mW2[k * 16 + o];
  h2 = siluf(h2);
  float contrib = h2 * mW3[o] + ((o == 0) ? mb3[0] : 0.f);
  block_reduce_store(contrib, learn_part);
}

// ---------------- final reduction ----------------
__global__ __launch_bounds__(256) void k_finalize(
    const float* __restrict__ coul_part, int nc,
    const float* __restrict__ learn_part, int nl,
    float* __restrict__ out)
{
  __shared__ float sred[4];
  int tid = threadIdx.x;
  float v = 0.f;
  for (int i = tid; i < nc; i += 256) v += coul_part[i];
  for (int i = tid; i < nl; i += 256) v += learn_part[i];
#pragma unroll
  for (int off = 32; off > 0; off >>= 1) v += __shfl_down(v, off, 64);
  if ((tid & 63) == 0) sred[tid >> 6] = v;
  __syncthreads();
  if (tid == 0) out[0] = sred[0] + sred[1] + sred[2] + sred[3];
}

extern "C" void kernel_launch(void* const* d_in, const int* in_sizes, int n_in,
                              void* d_out, int out_size, void* d_ws, size_t ws_size,
                              hipStream_t stream)
{
  const int*   species = (const int*)d_in[0];
  const int*   src     = (const int*)d_in[1];
  const int*   dst     = (const int*)d_in[2];
  const float* rel_pos = (const float*)d_in[3];
  const float* emb     = (const float*)d_in[4];
  const float* kv_W1   = (const float*)d_in[5];
  const float* kv_b1   = (const float*)d_in[6];
  const float* kv_W2   = (const float*)d_in[7];
  const float* kv_b2   = (const float*)d_in[8];
  const float* kv_W3   = (const float*)d_in[9];
  const float* kv_b3   = (const float*)d_in[10];
  const float* Wq      = (const float*)d_in[11];
  const float* Wproj   = (const float*)d_in[12];
  const float* fin_W1  = (const float*)d_in[13];
  const float* fin_b1  = (const float*)d_in[14];
  const float* fin_W2  = (const float*)d_in[15];
  const float* fin_b2  = (const float*)d_in[16];
  const float* fin_W3  = (const float*)d_in[17];
  const float* fin_b3  = (const float*)d_in[18];
  const float* Wself   = (const float*)d_in[19];
  const float* mlp_W1  = (const float*)d_in[20];
  const float* mlp_b1  = (const float*)d_in[21];
  const float* mlp_W2  = (const float*)d_in[22];
  const float* mlp_b2  = (const float*)d_in[23];
  const float* mlp_W3  = (const float*)d_in[24];
  const float* mlp_b3  = (const float*)d_in[25];

  const int N = in_sizes[0];
  const int E = in_sizes[1];
  const int nblk_e = (E + 255) / 256;
  const int nblk_n = (N + 255) / 256;
  const int nblk_f = N / 16;

  char* p = (char*)d_ws;
  auto alloc = [&](size_t bytes) -> void* {
    void* r = (void*)p;
    p += (bytes + 255) & ~(size_t)255;
    return r;
  };
  float*    dist_   = (float*)alloc((size_t)E * 4);
  float*    scale_  = (float*)alloc((size_t)E * 4);
  float*    distP   = (float*)alloc((size_t)E * 4);
  float*    scaleP  = (float*)alloc((size_t)E * 4);
  int*      srcP    = (int*)  alloc((size_t)E * 4);
  int*      perm    = (int*)  alloc((size_t)E * 4);
  unsigned* kvB     = (unsigned*)alloc((size_t)E * 8 * 4);
  float*    xA      = (float*)alloc((size_t)N * 16 * 4);
  float*    xB      = (float*)alloc((size_t)N * 16 * 4);
  float*    xsum    = (float*)alloc((size_t)N * 16 * 4);
  float*    q       = (float*)alloc((size_t)N * 8 * 4);
  int*      cnt     = (int*)  alloc((size_t)N * 4);
  int*      row_ptr = (int*)  alloc((size_t)(N + 1) * 4);
  int*      row_cur = (int*)  alloc((size_t)N * 4);
  int*      bsum    = (int*)  alloc(128 * 4);
  int*      boff    = (int*)  alloc(128 * 4);
  uint4*    WF      = (uint4*)alloc((size_t)5 * 21 * 64 * 16);
  float*    coul_part  = (float*)alloc((size_t)nblk_e * 4);
  float*    learn_part = (float*)alloc((size_t)nblk_f * 4);

  dim3 blk(256);
  dim3 egrid(nblk_e);
  dim3 cgrid(E / 64);
  dim3 ngrid(nblk_n);
  dim3 augrid(N / 16);
  dim3 fgrid(nblk_f);

  hipMemsetAsync(cnt, 0, (size_t)N * 4, stream);

  k_prepack<<<dim3(27), blk, 0, stream>>>(kv_W3, kv_b3, fin_W3, fin_b3,
                                          kv_W2, fin_W2, kv_W1, fin_W1, WF);

  k_pre<<<egrid, blk, 0, stream>>>(species, src, dst, rel_pos, dist_, scale_,
                                   cnt, coul_part, E);
  k_scan1<<<ngrid, blk, 0, stream>>>(cnt, row_ptr, bsum);
  k_scan2<<<dim3(1), dim3(128), 0, stream>>>(bsum, boff);
  k_scan3<<<ngrid, blk, 0, stream>>>(row_ptr, row_cur, boff, N, E);
  k_scatter_perm<<<egrid, blk, 0, stream>>>(dst, row_cur, perm, E);
  k_permute<<<egrid, blk, 0, stream>>>(perm, src, dist_, scale_,
                                       srcP, distP, scaleP, E);

  k_node_init<<<ngrid, blk, 0, stream>>>(species, emb, Wq, xA, q, N);

  float* xin = xA;
  float* xout = xB;
  for (int l = 0; l < 4; l++) {
    const float* W1 = kv_W1 + (size_t)l * 16 * 32;
    const float* B1 = kv_b1 + (size_t)l * 32;
    const float* B2 = kv_b2 + (size_t)l * 32;
    const uint4* WFl = WF + (size_t)l * 21 * 64;
    const float* Wqn = Wq + (size_t)((l < 3) ? (l + 1) : 0) * 8 * 16;
    if (l == 0) {
      k_edge_conv<0><<<cgrid, blk, 0, stream>>>(srcP, scaleP, distP, xsum, xin,
                                                W1, B1, B2, WFl, kvB, E);
    } else {
      k_edge_conv<2><<<cgrid, blk, 0, stream>>>(srcP, scaleP, distP, xsum, xin,
                                                W1, B1, B2, WFl, kvB, E);
    }
    if (l == 0) {
      k_agg_update<true><<<augrid, blk, 0, stream>>>(row_ptr, scaleP, kvB, q, xin,
                                                     Wproj, Wqn, xout, q, xsum, N);
    } else {
      k_agg_update<false><<<augrid, blk, 0, stream>>>(row_ptr, scaleP, kvB, q, xin,
                                                      Wproj + (size_t)l * 16 * 24, Wqn,
                                                      xout, q, xsum, N);
    }
    float* tmp = xin; xin = xout; xout = tmp;
  }

  k_edge_conv<2><<<cgrid, blk, 0, stream>>>(srcP, scaleP, distP, xsum, xin,
                                            fin_W1, fin_b1, fin_b2,
                                            WF + (size_t)4 * 21 * 64, kvB, E);
  k_feats_final<<<fgrid, blk, 0, stream>>>(row_ptr, kvB, xin, species, emb, Wself,
                                           mlp_W1, mlp_b1, mlp_W2, mlp_b2, mlp_W3, mlp_b3,
                                           learn_part, N);
  k_finalize<<<dim3(1), blk, 0, stream>>>(coul_part, nblk_e, learn_part, nblk_f,
                                          (float*)d_out);
}

// Round 6
// 369.740 us; speedup vs baseline: 1.2380x; 1.1051x over previous
//
#include <hip/hip_runtime.h>

constexpr float F_Y0     = 0.28209479177387814f;
constexpr float F_CUTOFF = 4.6f;

typedef short short8 __attribute__((ext_vector_type(8)));
typedef float f32x4  __attribute__((ext_vector_type(4)));
typedef float float2v __attribute__((ext_vector_type(2)));

__device__ __forceinline__ float siluf(float v) { return v / (1.0f + __expf(-v)); }

// gfx950 hardware packed fp32->bf16 (RNE): lo = cvt(a), hi = cvt(b)
__device__ __forceinline__ unsigned pk2(float a, float b) {
  unsigned r;
  asm("v_cvt_pk_bf16_f32 %0, %1, %2" : "=v"(r) : "v"(a), "v"(b));
  return r;
}
// extract bf16 half h (0=lo,1=hi) of dword d as fp32
__device__ __forceinline__ float xbf(unsigned d, int h) {
  return __uint_as_float(h ? (d & 0xffff0000u) : (d << 16));
}
// packed fp32 multiply (full-rate VOP3P on CDNA)
__device__ __forceinline__ float2v pkmul2(float2v a, float2v b) {
  float2v d;
  asm("v_pk_mul_f32 %0, %1, %2" : "=v"(d) : "v"(a), "v"(b));
  return d;
}

union FragU { uint4 u; short8 s; };

__device__ __forceinline__ void load16(const float* p, float* r) {
  const float4* p4 = (const float4*)p;
#pragma unroll
  for (int i = 0; i < 4; i++) {
    float4 t = p4[i];
    r[4*i] = t.x; r[4*i+1] = t.y; r[4*i+2] = t.z; r[4*i+3] = t.w;
  }
}
__device__ __forceinline__ void store16(float* p, const float* r) {
  float4* p4 = (float4*)p;
#pragma unroll
  for (int i = 0; i < 4; i++) p4[i] = make_float4(r[4*i], r[4*i+1], r[4*i+2], r[4*i+3]);
}

// block-level sum of one float per thread -> part[blockIdx.x]
__device__ __forceinline__ void block_reduce_store(float v, float* part) {
  __shared__ float sred[4];
  int tid = threadIdx.x;
#pragma unroll
  for (int off = 32; off > 0; off >>= 1) v += __shfl_down(v, off, 64);
  if ((tid & 63) == 0) sred[tid >> 6] = v;
  __syncthreads();
  if (tid == 0) part[blockIdx.x] = sred[0] + sred[1] + sred[2] + sred[3];
}

// ---------------- per-edge precompute (+ CSR histogram fused) ----------------
// Dead-edge compaction. CRITICAL: the liveness predicate here (sc > 0) must be
// IDENTICAL to k_scatter_perm's (scale_[e] > 0). Edges with dist just under
// CUTOFF underflow sc to 0.0f; they contribute nothing (scale multiplies every
// contribution) and must be counted dead in BOTH places, else perm gets
// unwritten (poison) slots.
__global__ __launch_bounds__(256) void k_pre(
    const int* __restrict__ species, const int* __restrict__ src, const int* __restrict__ dst,
    const float* __restrict__ rel_pos,
    float* __restrict__ dist_, float* __restrict__ scale_,
    int* __restrict__ cnt,
    float* __restrict__ coul_part,
    int* __restrict__ srcP, float* __restrict__ distP, float* __restrict__ scaleP, int E)
{
  __shared__ float zpow[128];
  int tid = threadIdx.x;
  if (tid < 128) zpow[tid] = __powf((float)tid, 0.23f);
  __syncthreads();

  int e = blockIdx.x * 256 + tid;
  float ce = 0.0f;
  if (e < E) {
    float px = rel_pos[3*(size_t)e + 0];
    float py = rel_pos[3*(size_t)e + 1];
    float pz = rel_pos[3*(size_t)e + 2];
    float dist = sqrtf(px*px + py*py + pz*pz);
    float xc = dist * (1.0f / F_CUTOFF);
    bool in_cut = dist < F_CUTOFF;
    float x2 = in_cut ? xc * xc : 0.0f;
    x2 = fminf(x2, 1.0f - 1e-6f);
    float sc = in_cut ? __expf(3.0f - 3.0f / (1.0f - x2)) : 0.0f;
    dist_[e] = dist;
    scale_[e] = sc;
    srcP[e]   = 0;        // pad defaults (safe reads for straddling tiles)
    distP[e]  = 1.0f;
    scaleP[e] = 0.0f;
    if (sc > 0.0f) {      // SAME predicate as k_scatter_perm
      atomicAdd(&cnt[dst[e]], 1);
      int spu = species[src[e]], spv = species[dst[e]];
      float Zu = (float)spu;
      float Zv = (float)spv;
      float raw = 0.529f * Zu * Zv / (2.0f * dist);
      float au = 0.8854f * 0.529f / (zpow[spu] + zpow[spv]);
      float xx = dist / au;
      float screen = 0.1818f   * __expf(-3.2f    * xx)
                   + 0.5099f   * __expf(-0.9423f * xx)
                   + 0.2802f   * __expf(-0.4028f * xx)
                   + 0.02817f  * __expf(-0.2016f * xx);
      ce = raw * screen * sc;
    }
  }
  block_reduce_store(ce, coul_part);
}

// ---------------- CSR scans ----------------
__global__ __launch_bounds__(256) void k_scan1(
    const int* __restrict__ cnt, int* __restrict__ row_ptr, int* __restrict__ bsum)
{
  __shared__ int s[256];
  int tid = threadIdx.x;
  int n = blockIdx.x * 256 + tid;
  int v = cnt[n];
  s[tid] = v;
  __syncthreads();
#pragma unroll
  for (int off = 1; off < 256; off <<= 1) {
    int t = (tid >= off) ? s[tid - off] : 0;
    __syncthreads();
    s[tid] += t;
    __syncthreads();
  }
  row_ptr[n] = s[tid] - v;
  if (tid == 255) bsum[blockIdx.x] = s[255];
}

__global__ __launch_bounds__(128) void k_scan2(int* __restrict__ bsum, int* __restrict__ boff)
{
  __shared__ int s[128];
  int tid = threadIdx.x;
  int v = bsum[tid];
  s[tid] = v;
  __syncthreads();
#pragma unroll
  for (int off = 1; off < 128; off <<= 1) {
    int t = (tid >= off) ? s[tid - off] : 0;
    __syncthreads();
    s[tid] += t;
    __syncthreads();
  }
  boff[tid] = s[tid] - v;
}

__global__ __launch_bounds__(256) void k_scan3(
    int* __restrict__ row_ptr, int* __restrict__ row_cur,
    const int* __restrict__ boff, const int* __restrict__ cnt, int N)
{
  int n = blockIdx.x * 256 + threadIdx.x;
  int rp = row_ptr[n] + boff[blockIdx.x];
  row_ptr[n] = rp;
  row_cur[n] = rp;
  if (n == N - 1) row_ptr[N] = rp + cnt[n];   // = E_act (live edges)
}

__global__ __launch_bounds__(256) void k_scatter_perm(
    const int* __restrict__ dst, const float* __restrict__ scale_,
    int* __restrict__ row_cur,
    int* __restrict__ perm, int E)
{
  int e = blockIdx.x * 256 + threadIdx.x;
  if (e >= E) return;
  if (scale_[e] > 0.0f) {
    int pos = atomicAdd(&row_cur[dst[e]], 1);
    perm[pos] = e;
  }
}

__global__ __launch_bounds__(256) void k_permute(
    const int* __restrict__ perm,
    const int* __restrict__ src, const float* __restrict__ dist_, const float* __restrict__ scale_,
    int* __restrict__ srcP, float* __restrict__ distP, float* __restrict__ scaleP,
    const int* __restrict__ eactp)
{
  int i = blockIdx.x * 256 + threadIdx.x;
  if (i >= eactp[0]) return;
  int e = perm[i];
  srcP[i]   = src[e];
  distP[i]  = dist_[e];
  scaleP[i] = scale_[e];
}

// ---------------- weight prepack: per layer 21 bf16 B-fragments ----------------
// NOTE: W2 fragments (f=17,18) are k-interleaved to match the pair layout
// (m, m+16) that h1 is stored in: physical k position p holds logical
// row m(p) = (p&1) ? 16+(p>>1) : (p>>1).
__global__ __launch_bounds__(256) void k_prepack(
    const float* __restrict__ kv_W3, const float* __restrict__ kv_b3,
    const float* __restrict__ fin_W3, const float* __restrict__ fin_b3,
    const float* __restrict__ kv_W2, const float* __restrict__ fin_W2,
    const float* __restrict__ kv_W1, const float* __restrict__ fin_W1,
    uint4* __restrict__ WF)
{
  int t = blockIdx.x * 256 + threadIdx.x;
  if (t >= 5 * 21 * 64) return;
  int lyr = t / (21 * 64);
  int rem = t - lyr * 21 * 64;
  int f = rem >> 6;
  int l = rem & 63;
  int qq = l >> 4;
  int o = l & 15;
  const float* W3 = (lyr < 4) ? (kv_W3 + (size_t)lyr * 32 * 256) : fin_W3;
  const float* B3 = (lyr < 4) ? (kv_b3 + (size_t)lyr * 256) : fin_b3;
  const float* W2 = (lyr < 4) ? (kv_W2 + (size_t)lyr * 32 * 32) : fin_W2;
  const float* W1 = (lyr < 4) ? (kv_W1 + (size_t)lyr * 16 * 32) : fin_W1;
  float v[8];
#pragma unroll
  for (int j = 0; j < 8; j++) {
    if (f < 16) {
      int kk = f * 32 + qq * 8 + j;
      int m = kk >> 4, i = kk & 15;
      v[j] = W3[m * 256 + o * 16 + i];
    } else if (f == 16) {
      int r = qq * 8 + j;
      int mp = r >> 4, i = r & 15;
      v[j] = mp ? 0.0f : B3[o * 16 + i];
    } else if (f < 19) {
      int c = f - 17;
      int p = qq * 8 + j;                       // physical k position
      int m = (p & 1) ? (16 + (p >> 1)) : (p >> 1);  // pair-interleave
      v[j] = W2[m * 32 + c * 16 + o];
    } else {
      int c = f - 19;
      int k = qq * 8 + j;
      v[j] = (k < 16) ? W1[k * 32 + c * 16 + o] : 0.0f;
    }
  }
  uint4 dw;
  dw.x = pk2(v[0], v[1]);
  dw.y = pk2(v[2], v[3]);
  dw.z = pk2(v[4], v[5]);
  dw.w = pk2(v[6], v[7]);
  WF[t] = dw;
}

// ---------------- node init (x, q0; semb read on-demand later) ----------------
__global__ __launch_bounds__(256) void k_node_init(
    const int* __restrict__ species, const float* __restrict__ emb,
    const float* __restrict__ Wq0,
    float* __restrict__ x, float* __restrict__ q, int N)
{
  int n = blockIdx.x * 256 + threadIdx.x;
  if (n >= N) return;
  int sp = species[n] - 1;
  float xv[16];
  load16(emb + (size_t)sp * 16, xv);
  store16(x + (size_t)n * 16, xv);
  float qv[8];
#pragma unroll
  for (int h = 0; h < 8; h++) {
    float a = 0.f;
#pragma unroll
    for (int i = 0; i < 16; i++) a += Wq0[h * 16 + i] * xv[i];
    qv[h] = a;
  }
  float4* qp = (float4*)(q + (size_t)n * 8);
  qp[0] = make_float4(qv[0], qv[1], qv[2], qv[3]);
  qp[1] = make_float4(qv[4], qv[5], qv[6], qv[7]);
}

// ---------------- heavy edge conv: WAVE-LOCAL, zero __syncthreads ----------
// Each wave owns 16 edges end-to-end in a wave-private LDS region.
// LDS aliasing: P [0,1024) overlays the staging buffers {xsS,xsB,efB,h1P},
// which are all dead before the first P write (consumed by the h1/h2 MFMAs
// or pulled into registers: xs2, bias A-frag, hmv). Same-wave DS ops are
// processed in issue order and every P-write's data has a true register
// dependency on those reads, so the WAR overlap is safe.
// Per-wave: 1344 dw = 5376 B; block = 21504 B -> 7 blocks/CU (28 waves/CU).
// Blocks fully past E_act (row_ptr[N]) exit immediately (dead-edge compaction).
template <int MODE>
__global__ __launch_bounds__(256, 7) void k_edge_conv(
    const int* __restrict__ srcP,
    const float* __restrict__ scaleP, const float* __restrict__ distP,
    const float* __restrict__ xsum, const float* __restrict__ x,
    const float* __restrict__ W1, const float* __restrict__ B1,
    const float* __restrict__ B2,
    const uint4* __restrict__ WF,
    unsigned* __restrict__ kvB, const int* __restrict__ eactp)
{
  if (blockIdx.x * 64 >= eactp[0]) return;
  __shared__ unsigned smem[4 * 1344];
  int tid = threadIdx.x;
  int w = __builtin_amdgcn_readfirstlane(tid >> 6);
  int l = tid & 63;
  int quad = l >> 4;
  int lo = l & 15;
  unsigned* WS  = smem + w * 1344;     // per-wave private region (5376 B)
  unsigned* P   = WS;                  // [0,1024)    quarter-P (swizzled), aliases:
  float*    xsS = (float*)WS;          //   [0,320)   16 x 20 f32 x[src]
  unsigned* xsB = WS + 320;            //   [320,512) 16 x 12 (8 used) bf16 pairs x
  unsigned* efB = WS + 512;            //   [512,704) 16 x 12 bf16 pairs ef
  unsigned* h1P = WS + 704;            //   [704,1024) 16 x 20 (16 used) pairs (m,m+16)
  unsigned* h2P = WS + 1024;           // [1024,1344) 16 x 20 pairs / f32 kv stage

  int ebw = blockIdx.x * 64 + w * 16;

  // ---- early independent global loads (off the critical chain) ----
  float b2a = B2[lo], b2b = B2[16 + lo];
  float scv[4];
#pragma unroll
  for (int r = 0; r < 4; r++) scv[r] = scaleP[ebw + quad * 4 + r];

  // ---- gather (4 lanes per edge, wave-local) ----
  {
    int e4 = l >> 2, c4 = l & 3;
    int s4 = srcP[ebw + e4];
    float4 xv4 = ((const float4*)(x + (size_t)s4 * 16))[c4];
    float4 ev4;
    if (MODE == 2) {
      ev4 = ((const float4*)(xsum + (size_t)s4 * 16))[c4];
      if (c4 == 3) ev4.w += distP[ebw + e4];
    }
    *(float4*)&xsS[e4 * 20 + c4 * 4] = xv4;
    uint2 xp; xp.x = pk2(xv4.x, xv4.y); xp.y = pk2(xv4.z, xv4.w);
    *(uint2*)&xsB[e4 * 12 + c4 * 2] = xp;
    if (MODE == 2) {
      uint2 ep; ep.x = pk2(ev4.x, ev4.y); ep.y = pk2(ev4.z, ev4.w);
      *(uint2*)&efB[e4 * 12 + c4 * 2] = ep;
    }
  }

  // ---- h1 -> h1P as bf16 pairs: dword d of row e holds (m=d, m=d+16) ----
  if (MODE == 0) {
    float dd = distP[ebw + lo];
#pragma unroll
    for (int jj = 0; jj < 4; jj++) {
      int d = quad * 4 + jj;
      float v0 = fmaxf(B1[d]      + dd * W1[15 * 32 + d],      0.f);
      float v1 = fmaxf(B1[d + 16] + dd * W1[15 * 32 + d + 16], 0.f);
      h1P[lo * 20 + d] = pk2(v0, v1);
    }
  } else {
    float b1a = B1[lo], b1b = B1[16 + lo];
    FragU a, b0, b1;
    uint4 r = *(const uint4*)&efB[lo * 12 + (quad & 1) * 4];
    uint4 z = make_uint4(0, 0, 0, 0);
    a.u = (quad >= 2) ? z : r;
    b0.u = WF[19 * 64 + l];
    b1.u = WF[20 * 64 + l];
    f32x4 c0 = {0.f, 0.f, 0.f, 0.f};
    f32x4 c1 = {0.f, 0.f, 0.f, 0.f};
    c0 = __builtin_amdgcn_mfma_f32_16x16x32_bf16(a.s, b0.s, c0, 0, 0, 0);
    c1 = __builtin_amdgcn_mfma_f32_16x16x32_bf16(a.s, b1.s, c1, 0, 0, 0);
#pragma unroll
    for (int r2 = 0; r2 < 4; r2++)
      h1P[(quad * 4 + r2) * 20 + lo] =
          pk2(fmaxf(c0[r2] + b1a, 0.f), fmaxf(c1[r2] + b1b, 0.f));
  }

  // ---- h2 via MFMA (W2 prepacked pair-interleaved) -> h2P pairs (m,m+16) ----
  {
    FragU a, b0, b1;
    a.u = *(const uint4*)&h1P[lo * 20 + quad * 4];
    b0.u = WF[17 * 64 + l];
    b1.u = WF[18 * 64 + l];
    f32x4 hc0 = {0.f, 0.f, 0.f, 0.f};
    f32x4 hc1 = {0.f, 0.f, 0.f, 0.f};
    hc0 = __builtin_amdgcn_mfma_f32_16x16x32_bf16(a.s, b0.s, hc0, 0, 0, 0);
    hc1 = __builtin_amdgcn_mfma_f32_16x16x32_bf16(a.s, b1.s, hc1, 0, 0, 0);
#pragma unroll
    for (int r = 0; r < 4; r++)
      h2P[(quad * 4 + r) * 20 + lo] =
          pk2(fmaxf(hc0[r] + b2a, 0.f), fmaxf(hc1[r] + b2b, 0.f));
  }

  // ---- pull P-build operands into registers (frees the staging region) ----
  float2v xs2[8];
  {
    const float4* xr = (const float4*)&xsS[lo * 20];   // broadcast reads
#pragma unroll
    for (int i = 0; i < 4; i++) {
      float4 t = xr[i];
      float2v a; a.x = t.x; a.y = t.y;
      float2v b; b.x = t.z; b.y = t.w;
      xs2[2 * i]     = a;
      xs2[2 * i + 1] = b;
    }
  }
  uint2 hA = *(const uint2*)&h2P[lo * 20 + quad * 2];      // m = 2q..2q+1 (+16 hi)
  uint2 hB = *(const uint2*)&h2P[lo * 20 + 8 + quad * 2];  // m = 8+2q..  (+16 hi)
  float hmv[8];
  hmv[0] = xbf(hA.x, 0); hmv[1] = xbf(hA.y, 0);   // quarter 0: m in [0,8)
  hmv[2] = xbf(hB.x, 0); hmv[3] = xbf(hB.y, 0);   // quarter 1: m in [8,16)
  hmv[4] = xbf(hA.x, 1); hmv[5] = xbf(hA.y, 1);   // quarter 2: m in [16,24)
  hmv[6] = xbf(hB.x, 1); hmv[7] = xbf(hB.y, 1);   // quarter 3: m in [24,32)

  // ---- bias term: kv += x @ B3 (reads xsB before P overwrites it) ----
  f32x4 acc = {0.f, 0.f, 0.f, 0.f};
  {
    FragU a, b;
    uint4 r = *(const uint4*)&xsB[lo * 12 + (quad & 1) * 4];
    uint4 z = make_uint4(0, 0, 0, 0);
    a.u = (quad >= 2) ? z : r;
    b.u = WF[16 * 64 + l];
    acc = __builtin_amdgcn_mfma_f32_16x16x32_bf16(a.s, b.s, acc, 0, 0, 0);
  }

  // ---- 4 quarter-phases: build 2 m-rows of P per lane, 4 MFMAs per phase ----
#pragma unroll
  for (int q = 0; q < 4; q++) {
#pragma unroll
    for (int j = 0; j < 2; j++) {
      float hm = hmv[q * 2 + j];
      float2v hm2; hm2.x = hm; hm2.y = hm;
      uint4 d0, d1;
      float2v p0 = pkmul2(hm2, xs2[0]);
      float2v p1 = pkmul2(hm2, xs2[1]);
      float2v p2 = pkmul2(hm2, xs2[2]);
      float2v p3 = pkmul2(hm2, xs2[3]);
      d0.x = pk2(p0.x, p0.y); d0.y = pk2(p1.x, p1.y);
      d0.z = pk2(p2.x, p2.y); d0.w = pk2(p3.x, p3.y);
      float2v p4 = pkmul2(hm2, xs2[4]);
      float2v p5 = pkmul2(hm2, xs2[5]);
      float2v p6 = pkmul2(hm2, xs2[6]);
      float2v p7 = pkmul2(hm2, xs2[7]);
      d1.x = pk2(p4.x, p4.y); d1.y = pk2(p5.x, p5.y);
      d1.z = pk2(p6.x, p6.y); d1.w = pk2(p7.x, p7.y);
      int cb = quad * 4 + j * 2;                 // chunk base (m_local*2)
      *(uint4*)&P[lo * 64 + (((cb)     ^ lo) << 2)] = d0;
      *(uint4*)&P[lo * 64 + (((cb + 1) ^ lo) << 2)] = d1;
    }
#pragma unroll
    for (int t = 0; t < 4; t++) {
      FragU a, b;
      a.u = *(const uint4*)&P[lo * 64 + (((t * 4 + quad) ^ lo) << 2)];
      b.u = WF[(q * 4 + t) * 64 + l];
      acc = __builtin_amdgcn_mfma_f32_16x16x32_bf16(a.s, b.s, acc, 0, 0, 0);
    }
  }

  // ---- kv epilogue: scale, stage f32 (reuse h2P), pack, coalesced store ----
#pragma unroll
  for (int r = 0; r < 4; r++) {
    int e = quad * 4 + r;
    ((float*)h2P)[e * 20 + lo] = acc[r] * (F_Y0 * scv[r]);
  }
  {
    int e2 = l >> 2, c = l & 3;
    const float* row = (const float*)&h2P[e2 * 20 + c * 4];
    float4 t = *(const float4*)row;
    uint2 pkd;
    pkd.x = pk2(t.x, t.y);
    pkd.y = pk2(t.z, t.w);
    *(uint2*)(kvB + ((size_t)(ebw + e2) * 8 + c * 2)) = pkd;
  }
}

// ---------------- fused softmax-gather + node update (16 threads/node) ------
// Degree loop software-pipelined 4-deep: 12 independent loads issue before
// the first exp consumes them.
template <bool INIT>
__global__ __launch_bounds__(256) void k_agg_update(
    const int* __restrict__ row_ptr, const float* __restrict__ scaleP,
    const unsigned* __restrict__ kvB, const float* __restrict__ qin,
    const float* __restrict__ xin,
    const float* __restrict__ Wproj, const float* __restrict__ Wq_next,
    float* __restrict__ xout, float* __restrict__ qout, float* __restrict__ xsum, int N)
{
  __shared__ float sA[16 * 8];
  __shared__ float sX[16 * 17];
  __shared__ float sN[16 * 17];
  int tid = threadIdx.x;
  int nl = tid >> 4;
  int t16 = tid & 15;
  int h = t16 & 7;
  int p = t16 >> 3;
  int n = blockIdx.x * 16 + nl;
  int hd = h >> 1, hh = h & 1;

  float qh = qin[(size_t)n * 8 + h];
  int j0 = row_ptr[n], j1 = row_ptr[n + 1];
  float num = 0.f, den = 0.f;
  int j = j0 + p;
  for (; j + 6 < j1; j += 8) {
    unsigned va = kvB[(size_t)j * 8 + hd];
    unsigned ka = kvB[(size_t)j * 8 + 4 + hd];
    unsigned vb = kvB[(size_t)(j + 2) * 8 + hd];
    unsigned kb = kvB[(size_t)(j + 2) * 8 + 4 + hd];
    unsigned vc = kvB[(size_t)(j + 4) * 8 + hd];
    unsigned kc = kvB[(size_t)(j + 4) * 8 + 4 + hd];
    unsigned vd = kvB[(size_t)(j + 6) * 8 + hd];
    unsigned kd = kvB[(size_t)(j + 6) * 8 + 4 + hd];
    float sa = scaleP[j];
    float sb = scaleP[j + 2];
    float sc = scaleP[j + 4];
    float sd = scaleP[j + 6];
    float wa = sa * __expf(fminf(xbf(ka, hh) * qh, 60.0f));
    float wb = sb * __expf(fminf(xbf(kb, hh) * qh, 60.0f));
    float wc = sc * __expf(fminf(xbf(kc, hh) * qh, 60.0f));
    float wd = sd * __expf(fminf(xbf(kd, hh) * qh, 60.0f));
    num += wa * xbf(va, hh) + wb * xbf(vb, hh) + wc * xbf(vc, hh) + wd * xbf(vd, hh);
    den += (wa + wb) + (wc + wd);
  }
  for (; j < j1; j += 2) {
    float val = xbf(kvB[(size_t)j * 8 + hd], hh);
    float key = xbf(kvB[(size_t)j * 8 + 4 + hd], hh);
    float lg = fminf(key * qh, 60.0f);
    float wv = scaleP[j] * __expf(lg);
    num += wv * val;
    den += wv;
  }
  num += __shfl_xor(num, 8, 64);
  den += __shfl_xor(den, 8, 64);
  if (p == 0) sA[nl * 8 + h] = num / fmaxf(den, 1e-20f);
  sX[nl * 17 + t16] = xin[(size_t)n * 16 + t16];
  __syncthreads();

  float cat[24];
#pragma unroll
  for (int jj = 0; jj < 8; jj++) cat[jj] = sA[nl * 8 + jj];
#pragma unroll
  for (int jj = 0; jj < 16; jj++) cat[8 + jj] = sX[nl * 17 + jj];
  float xn = 0.f;
#pragma unroll
  for (int jj = 0; jj < 24; jj++) xn += Wproj[t16 * 24 + jj] * cat[jj];
  xout[(size_t)n * 16 + t16] = xn;
  if (INIT) {
    xsum[(size_t)n * 16 + t16] = xn;
  } else {
    xsum[(size_t)n * 16 + t16] += xn;
  }
  sN[nl * 17 + t16] = xn;
  __syncthreads();

  if (p == 0) {
    float a = 0.f;
#pragma unroll
    for (int i = 0; i < 16; i++) a += Wq_next[h * 16 + i] * sN[nl * 17 + i];
    qout[(size_t)n * 8 + h] = a;
  }
}

// ---------------- fused feats gather + final MLP (16 threads/node) ----------
// Gather loop batched 4-deep for load ILP.
__global__ __launch_bounds__(256) void k_feats_final(
    const int* __restrict__ row_ptr, const unsigned* __restrict__ kvB,
    const float* __restrict__ x,
    const int* __restrict__ species, const float* __restrict__ emb,
    const float* __restrict__ Wself,
    const float* __restrict__ mW1, const float* __restrict__ mb1,
    const float* __restrict__ mW2, const float* __restrict__ mb2,
    const float* __restrict__ mW3, const float* __restrict__ mb3,
    float* __restrict__ learn_part, int N)
{
  __shared__ float sX[16 * 20];
  __shared__ float sC[16 * 40];
  __shared__ float sH[16 * 20];
  int tid = threadIdx.x;
  int nl = tid >> 4;
  int o = tid & 15;
  int n = blockIdx.x * 16 + nl;
  int od = o >> 1, oh = o & 1;

  int j0 = row_ptr[n], j1 = row_ptr[n + 1];
  float ft = 0.f;
  int j = j0;
  for (; j + 3 < j1; j += 4) {
    unsigned a = kvB[(size_t)j * 8 + od];
    unsigned b = kvB[(size_t)(j + 1) * 8 + od];
    unsigned c = kvB[(size_t)(j + 2) * 8 + od];
    unsigned d = kvB[(size_t)(j + 3) * 8 + od];
    ft += (xbf(a, oh) + xbf(b, oh)) + (xbf(c, oh) + xbf(d, oh));
  }
  for (; j < j1; ++j) ft += xbf(kvB[(size_t)j * 8 + od], oh);

  if (o < 4) {
    float4 v = ((const float4*)(x + (size_t)n * 16))[o];
    *(float4*)&sX[nl * 20 + o * 4] = v;
  } else if (o < 8) {
    int sp = species[n] - 1;
    float4 v = ((const float4*)(emb + (size_t)sp * 16))[o - 4];
    *(float4*)&sC[nl * 40 + (o - 4) * 4] = v;
  }
  __syncthreads();

  float xv[16];
  load16(&sX[nl * 20], xv);
  float a = ft;
#pragma unroll
  for (int i = 0; i < 16; i++) a += Wself[o * 16 + i] * xv[i];
  sC[nl * 40 + 16 + o] = a;
  __syncthreads();

  float cat[32];
  load16(&sC[nl * 40], cat);
  load16(&sC[nl * 40 + 16], cat + 16);
  float hh = mb1[o];
#pragma unroll
  for (int k = 0; k < 32; k++) hh += cat[k] * mW1[k * 16 + o];
  hh = siluf(hh);
  sH[nl * 20 + o] = hh;
  __syncthreads();

  float hv[16];
  load16(&sH[nl * 20], hv);
  float h2 = mb2[o];
#pragma unroll
  for (int k = 0; k < 16; k++) h2 += hv[k] * mW2[k * 16 + o];
  h2 = siluf(h2);
  float contrib = h2 * mW3[o] + ((o == 0) ? mb3[0] : 0.f);
  block_reduce_store(contrib, learn_part);
}

// ---------------- final reduction ----------------
__global__ __launch_bounds__(256) void k_finalize(
    const float* __restrict__ coul_part, int nc,
    const float* __restrict__ learn_part, int nl,
    float* __restrict__ out)
{
  __shared__ float sred[4];
  int tid = threadIdx.x;
  float v = 0.f;
  for (int i = tid; i < nc; i += 256) v += coul_part[i];
  for (int i = tid; i < nl; i += 256) v += learn_part[i];
#pragma unroll
  for (int off = 32; off > 0; off >>= 1) v += __shfl_down(v, off, 64);
  if ((tid & 63) == 0) sred[tid >> 6] = v;
  __syncthreads();
  if (tid == 0) out[0] = sred[0] + sred[1] + sred[2] + sred[3];
}

extern "C" void kernel_launch(void* const* d_in, const int* in_sizes, int n_in,
                              void* d_out, int out_size, void* d_ws, size_t ws_size,
                              hipStream_t stream)
{
  const int*   species = (const int*)d_in[0];
  const int*   src     = (const int*)d_in[1];
  const int*   dst     = (const int*)d_in[2];
  const float* rel_pos = (const float*)d_in[3];
  const float* emb     = (const float*)d_in[4];
  const float* kv_W1   = (const float*)d_in[5];
  const float* kv_b1   = (const float*)d_in[6];
  const float* kv_W2   = (const float*)d_in[7];
  const float* kv_b2   = (const float*)d_in[8];
  const float* kv_W3   = (const float*)d_in[9];
  const float* kv_b3   = (const float*)d_in[10];
  const float* Wq      = (const float*)d_in[11];
  const float* Wproj   = (const float*)d_in[12];
  const float* fin_W1  = (const float*)d_in[13];
  const float* fin_b1  = (const float*)d_in[14];
  const float* fin_W2  = (const float*)d_in[15];
  const float* fin_b2  = (const float*)d_in[16];
  const float* fin_W3  = (const float*)d_in[17];
  const float* fin_b3  = (const float*)d_in[18];
  const float* Wself   = (const float*)d_in[19];
  const float* mlp_W1  = (const float*)d_in[20];
  const float* mlp_b1  = (const float*)d_in[21];
  const float* mlp_W2  = (const float*)d_in[22];
  const float* mlp_b2  = (const float*)d_in[23];
  const float* mlp_W3  = (const float*)d_in[24];
  const float* mlp_b3  = (const float*)d_in[25];

  const int N = in_sizes[0];
  const int E = in_sizes[1];
  const int nblk_e = (E + 255) / 256;
  const int nblk_n = (N + 255) / 256;
  const int nblk_f = N / 16;

  char* p = (char*)d_ws;
  auto alloc = [&](size_t bytes) -> void* {
    void* r = (void*)p;
    p += (bytes + 255) & ~(size_t)255;
    return r;
  };
  float*    dist_   = (float*)alloc((size_t)E * 4);
  float*    scale_  = (float*)alloc((size_t)E * 4);
  float*    distP   = (float*)alloc((size_t)E * 4);
  float*    scaleP  = (float*)alloc((size_t)E * 4);
  int*      srcP    = (int*)  alloc((size_t)E * 4);
  int*      perm    = (int*)  alloc((size_t)E * 4);
  unsigned* kvB     = (unsigned*)alloc((size_t)E * 8 * 4);
  float*    xA      = (float*)alloc((size_t)N * 16 * 4);
  float*    xB      = (float*)alloc((size_t)N * 16 * 4);
  float*    xsum    = (float*)alloc((size_t)N * 16 * 4);
  float*    q       = (float*)alloc((size_t)N * 8 * 4);
  int*      cnt     = (int*)  alloc((size_t)N * 4);
  int*      row_ptr = (int*)  alloc((size_t)(N + 1) * 4);
  int*      row_cur = (int*)  alloc((size_t)N * 4);
  int*      bsum    = (int*)  alloc(128 * 4);
  int*      boff    = (int*)  alloc(128 * 4);
  uint4*    WF      = (uint4*)alloc((size_t)5 * 21 * 64 * 16);
  float*    coul_part  = (float*)alloc((size_t)nblk_e * 4);
  float*    learn_part = (float*)alloc((size_t)nblk_f * 4);

  const int* eactp = row_ptr + N;   // row_ptr[N] = number of live edges

  dim3 blk(256);
  dim3 egrid(nblk_e);
  dim3 cgrid(E / 64);
  dim3 ngrid(nblk_n);
  dim3 augrid(N / 16);
  dim3 fgrid(nblk_f);

  hipMemsetAsync(cnt, 0, (size_t)N * 4, stream);

  k_prepack<<<dim3(27), blk, 0, stream>>>(kv_W3, kv_b3, fin_W3, fin_b3,
                                          kv_W2, fin_W2, kv_W1, fin_W1, WF);

  k_pre<<<egrid, blk, 0, stream>>>(species, src, dst, rel_pos, dist_, scale_,
                                   cnt, coul_part, srcP, distP, scaleP, E);
  k_scan1<<<ngrid, blk, 0, stream>>>(cnt, row_ptr, bsum);
  k_scan2<<<dim3(1), dim3(128), 0, stream>>>(bsum, boff);
  k_scan3<<<ngrid, blk, 0, stream>>>(row_ptr, row_cur, boff, cnt, N);
  k_scatter_perm<<<egrid, blk, 0, stream>>>(dst, scale_, row_cur, perm, E);
  k_permute<<<egrid, blk, 0, stream>>>(perm, src, dist_, scale_,
                                       srcP, distP, scaleP, eactp);

  k_node_init<<<ngrid, blk, 0, stream>>>(species, emb, Wq, xA, q, N);

  float* xin = xA;
  float* xout = xB;
  for (int l = 0; l < 4; l++) {
    const float* W1 = kv_W1 + (size_t)l * 16 * 32;
    const float* B1 = kv_b1 + (size_t)l * 32;
    const float* B2 = kv_b2 + (size_t)l * 32;
    const uint4* WFl = WF + (size_t)l * 21 * 64;
    const float* Wqn = Wq + (size_t)((l < 3) ? (l + 1) : 0) * 8 * 16;
    if (l == 0) {
      k_edge_conv<0><<<cgrid, blk, 0, stream>>>(srcP, scaleP, distP, xsum, xin,
                                                W1, B1, B2, WFl, kvB, eactp);
    } else {
      k_edge_conv<2><<<cgrid, blk, 0, stream>>>(srcP, scaleP, distP, xsum, xin,
                                                W1, B1, B2, WFl, kvB, eactp);
    }
    if (l == 0) {
      k_agg_update<true><<<augrid, blk, 0, stream>>>(row_ptr, scaleP, kvB, q, xin,
                                                     Wproj, Wqn, xout, q, xsum, N);
    } else {
      k_agg_update<false><<<augrid, blk, 0, stream>>>(row_ptr, scaleP, kvB, q, xin,
                                                      Wproj + (size_t)l * 16 * 24, Wqn,
                                                      xout, q, xsum, N);
    }
    float* tmp = xin; xin = xout; xout = tmp;
  }

  k_edge_conv<2><<<cgrid, blk, 0, stream>>>(srcP, scaleP, distP, xsum, xin,
                                            fin_W1, fin_b1, fin_b2,
                                            WF + (size_t)4 * 21 * 64, kvB, eactp);
  k_feats_final<<<fgrid, blk, 0, stream>>>(row_ptr, kvB, xin, species, emb, Wself,
                                           mlp_W1, mlp_b1, mlp_W2, mlp_b2, mlp_W3, mlp_b3,
                                           learn_part, N);
  k_finalize<<<dim3(1), blk, 0, stream>>>(coul_part, nblk_e, learn_part, nblk_f,
                                          (float*)d_out);
}

// Round 7
// 360.997 us; speedup vs baseline: 1.2680x; 1.0242x over previous
//
#include <hip/hip_runtime.h>

constexpr float F_Y0     = 0.28209479177387814f;
constexpr float F_CUTOFF = 4.6f;

typedef short short8 __attribute__((ext_vector_type(8)));
typedef float f32x4  __attribute__((ext_vector_type(4)));
typedef float float2v __attribute__((ext_vector_type(2)));

__device__ __forceinline__ float siluf(float v) { return v / (1.0f + __expf(-v)); }

// gfx950 hardware packed fp32->bf16 (RNE): lo = cvt(a), hi = cvt(b)
__device__ __forceinline__ unsigned pk2(float a, float b) {
  unsigned r;
  asm("v_cvt_pk_bf16_f32 %0, %1, %2" : "=v"(r) : "v"(a), "v"(b));
  return r;
}
// extract bf16 half h (0=lo,1=hi) of dword d as fp32
__device__ __forceinline__ float xbf(unsigned d, int h) {
  return __uint_as_float(h ? (d & 0xffff0000u) : (d << 16));
}
// packed fp32 multiply (full-rate VOP3P on CDNA)
__device__ __forceinline__ float2v pkmul2(float2v a, float2v b) {
  float2v d;
  asm("v_pk_mul_f32 %0, %1, %2" : "=v"(d) : "v"(a), "v"(b));
  return d;
}

union FragU { uint4 u; short8 s; };

__device__ __forceinline__ void load16(const float* p, float* r) {
  const float4* p4 = (const float4*)p;
#pragma unroll
  for (int i = 0; i < 4; i++) {
    float4 t = p4[i];
    r[4*i] = t.x; r[4*i+1] = t.y; r[4*i+2] = t.z; r[4*i+3] = t.w;
  }
}
__device__ __forceinline__ void store16(float* p, const float* r) {
  float4* p4 = (float4*)p;
#pragma unroll
  for (int i = 0; i < 4; i++) p4[i] = make_float4(r[4*i], r[4*i+1], r[4*i+2], r[4*i+3]);
}

// block-level sum of one float per thread -> part[blockIdx.x]
__device__ __forceinline__ void block_reduce_store(float v, float* part) {
  __shared__ float sred[4];
  int tid = threadIdx.x;
#pragma unroll
  for (int off = 32; off > 0; off >>= 1) v += __shfl_down(v, off, 64);
  if ((tid & 63) == 0) sred[tid >> 6] = v;
  __syncthreads();
  if (tid == 0) part[blockIdx.x] = sred[0] + sred[1] + sred[2] + sred[3];
}

// ---------------- per-edge precompute (+ CSR histogram fused) ----------------
// Dead-edge compaction. CRITICAL: the liveness predicate here (sc > 0) must be
// IDENTICAL to k_scatter_perm's (scale_[e] > 0).
__global__ __launch_bounds__(256) void k_pre(
    const int* __restrict__ species, const int* __restrict__ src, const int* __restrict__ dst,
    const float* __restrict__ rel_pos,
    float* __restrict__ dist_, float* __restrict__ scale_,
    int* __restrict__ cnt,
    float* __restrict__ coul_part,
    int* __restrict__ srcP, float* __restrict__ distP, float* __restrict__ scaleP, int E)
{
  __shared__ float zpow[128];
  int tid = threadIdx.x;
  if (tid < 128) zpow[tid] = __powf((float)tid, 0.23f);
  __syncthreads();

  int e = blockIdx.x * 256 + tid;
  float ce = 0.0f;
  if (e < E) {
    float px = rel_pos[3*(size_t)e + 0];
    float py = rel_pos[3*(size_t)e + 1];
    float pz = rel_pos[3*(size_t)e + 2];
    float dist = sqrtf(px*px + py*py + pz*pz);
    float xc = dist * (1.0f / F_CUTOFF);
    bool in_cut = dist < F_CUTOFF;
    float x2 = in_cut ? xc * xc : 0.0f;
    x2 = fminf(x2, 1.0f - 1e-6f);
    float sc = in_cut ? __expf(3.0f - 3.0f / (1.0f - x2)) : 0.0f;
    dist_[e] = dist;
    scale_[e] = sc;
    srcP[e]   = 0;        // pad defaults (safe reads for straddling tiles)
    distP[e]  = 1.0f;
    scaleP[e] = 0.0f;
    if (sc > 0.0f) {      // SAME predicate as k_scatter_perm
      atomicAdd(&cnt[dst[e]], 1);
      int spu = species[src[e]], spv = species[dst[e]];
      float Zu = (float)spu;
      float Zv = (float)spv;
      float raw = 0.529f * Zu * Zv / (2.0f * dist);
      float au = 0.8854f * 0.529f / (zpow[spu] + zpow[spv]);
      float xx = dist / au;
      float screen = 0.1818f   * __expf(-3.2f    * xx)
                   + 0.5099f   * __expf(-0.9423f * xx)
                   + 0.2802f   * __expf(-0.4028f * xx)
                   + 0.02817f  * __expf(-0.2016f * xx);
      ce = raw * screen * sc;
    }
  }
  block_reduce_store(ce, coul_part);
}

// ---------------- CSR scans ----------------
__global__ __launch_bounds__(256) void k_scan1(
    const int* __restrict__ cnt, int* __restrict__ row_ptr, int* __restrict__ bsum)
{
  __shared__ int s[256];
  int tid = threadIdx.x;
  int n = blockIdx.x * 256 + tid;
  int v = cnt[n];
  s[tid] = v;
  __syncthreads();
#pragma unroll
  for (int off = 1; off < 256; off <<= 1) {
    int t = (tid >= off) ? s[tid - off] : 0;
    __syncthreads();
    s[tid] += t;
    __syncthreads();
  }
  row_ptr[n] = s[tid] - v;
  if (tid == 255) bsum[blockIdx.x] = s[255];
}

__global__ __launch_bounds__(128) void k_scan2(int* __restrict__ bsum, int* __restrict__ boff)
{
  __shared__ int s[128];
  int tid = threadIdx.x;
  int v = bsum[tid];
  s[tid] = v;
  __syncthreads();
#pragma unroll
  for (int off = 1; off < 128; off <<= 1) {
    int t = (tid >= off) ? s[tid - off] : 0;
    __syncthreads();
    s[tid] += t;
    __syncthreads();
  }
  boff[tid] = s[tid] - v;
}

__global__ __launch_bounds__(256) void k_scan3(
    int* __restrict__ row_ptr, int* __restrict__ row_cur,
    const int* __restrict__ boff, const int* __restrict__ cnt, int N)
{
  int n = blockIdx.x * 256 + threadIdx.x;
  int rp = row_ptr[n] + boff[blockIdx.x];
  row_ptr[n] = rp;
  row_cur[n] = rp;
  if (n == N - 1) row_ptr[N] = rp + cnt[n];   // = E_act (live edges)
}

__global__ __launch_bounds__(256) void k_scatter_perm(
    const int* __restrict__ dst, const float* __restrict__ scale_,
    int* __restrict__ row_cur,
    int* __restrict__ perm, int E)
{
  int e = blockIdx.x * 256 + threadIdx.x;
  if (e >= E) return;
  if (scale_[e] > 0.0f) {
    int pos = atomicAdd(&row_cur[dst[e]], 1);
    perm[pos] = e;
  }
}

__global__ __launch_bounds__(256) void k_permute(
    const int* __restrict__ perm,
    const int* __restrict__ src, const float* __restrict__ dist_, const float* __restrict__ scale_,
    int* __restrict__ srcP, float* __restrict__ distP, float* __restrict__ scaleP,
    const int* __restrict__ eactp)
{
  int i = blockIdx.x * 256 + threadIdx.x;
  if (i >= eactp[0]) return;
  int e = perm[i];
  srcP[i]   = src[e];
  distP[i]  = dist_[e];
  scaleP[i] = scale_[e];
}

// ---------------- weight prepack: per layer 21 bf16 B-fragments ----------------
// NOTE: W2 fragments (f=17,18) are k-interleaved to match the pair layout
// (m, m+16) that h1 is stored in: physical k position p holds logical
// row m(p) = (p&1) ? 16+(p>>1) : (p>>1).
__global__ __launch_bounds__(256) void k_prepack(
    const float* __restrict__ kv_W3, const float* __restrict__ kv_b3,
    const float* __restrict__ fin_W3, const float* __restrict__ fin_b3,
    const float* __restrict__ kv_W2, const float* __restrict__ fin_W2,
    const float* __restrict__ kv_W1, const float* __restrict__ fin_W1,
    uint4* __restrict__ WF)
{
  int t = blockIdx.x * 256 + threadIdx.x;
  if (t >= 5 * 21 * 64) return;
  int lyr = t / (21 * 64);
  int rem = t - lyr * 21 * 64;
  int f = rem >> 6;
  int l = rem & 63;
  int qq = l >> 4;
  int o = l & 15;
  const float* W3 = (lyr < 4) ? (kv_W3 + (size_t)lyr * 32 * 256) : fin_W3;
  const float* B3 = (lyr < 4) ? (kv_b3 + (size_t)lyr * 256) : fin_b3;
  const float* W2 = (lyr < 4) ? (kv_W2 + (size_t)lyr * 32 * 32) : fin_W2;
  const float* W1 = (lyr < 4) ? (kv_W1 + (size_t)lyr * 16 * 32) : fin_W1;
  float v[8];
#pragma unroll
  for (int j = 0; j < 8; j++) {
    if (f < 16) {
      int kk = f * 32 + qq * 8 + j;
      int m = kk >> 4, i = kk & 15;
      v[j] = W3[m * 256 + o * 16 + i];
    } else if (f == 16) {
      int r = qq * 8 + j;
      int mp = r >> 4, i = r & 15;
      v[j] = mp ? 0.0f : B3[o * 16 + i];
    } else if (f < 19) {
      int c = f - 17;
      int p = qq * 8 + j;                       // physical k position
      int m = (p & 1) ? (16 + (p >> 1)) : (p >> 1);  // pair-interleave
      v[j] = W2[m * 32 + c * 16 + o];
    } else {
      int c = f - 19;
      int k = qq * 8 + j;
      v[j] = (k < 16) ? W1[k * 32 + c * 16 + o] : 0.0f;
    }
  }
  uint4 dw;
  dw.x = pk2(v[0], v[1]);
  dw.y = pk2(v[2], v[3]);
  dw.z = pk2(v[4], v[5]);
  dw.w = pk2(v[6], v[7]);
  WF[t] = dw;
}

// ---------------- node init (x, q0; semb read on-demand later) ----------------
__global__ __launch_bounds__(256) void k_node_init(
    const int* __restrict__ species, const float* __restrict__ emb,
    const float* __restrict__ Wq0,
    float* __restrict__ x, float* __restrict__ q, int N)
{
  int n = blockIdx.x * 256 + threadIdx.x;
  if (n >= N) return;
  int sp = species[n] - 1;
  float xv[16];
  load16(emb + (size_t)sp * 16, xv);
  store16(x + (size_t)n * 16, xv);
  float qv[8];
#pragma unroll
  for (int h = 0; h < 8; h++) {
    float a = 0.f;
#pragma unroll
    for (int i = 0; i < 16; i++) a += Wq0[h * 16 + i] * xv[i];
    qv[h] = a;
  }
  float4* qp = (float4*)(q + (size_t)n * 8);
  qp[0] = make_float4(qv[0], qv[1], qv[2], qv[3]);
  qp[1] = make_float4(qv[4], qv[5], qv[6], qv[7]);
}

// ---------------- heavy edge conv: WAVE-LOCAL, zero __syncthreads ----------
// Each wave owns 16 edges end-to-end in a wave-private LDS region.
// This version builds the W3 MFMA A-fragments IN REGISTERS (no P matrix in
// LDS): for fragment f, lane (quad,lo) needs A[lo][k=f*32+quad*8+j] =
// h2[m]*x[i] with a SINGLE m = 2f+(quad>>1) and i = (quad&1)*8+j. h2 is
// stored channel-permuted in LDS (position p=(c&1)*8+(c>>1) holds channels
// (c, c+16) as a bf16 pair) so each lane's 8 needed dwords are 2 b128 reads.
// Products and pk2 roundings are identical to the old P path -> bit-identical.
// Per-wave: 1344 dw = 5376 B; block = 21504 B -> 7 blocks/CU (28 waves/CU).
// Blocks fully past E_act (row_ptr[N]) exit immediately (dead-edge compaction).
template <int MODE>
__global__ __launch_bounds__(256, 7) void k_edge_conv(
    const int* __restrict__ srcP,
    const float* __restrict__ scaleP, const float* __restrict__ distP,
    const float* __restrict__ xsum, const float* __restrict__ x,
    const float* __restrict__ W1, const float* __restrict__ B1,
    const float* __restrict__ B2,
    const uint4* __restrict__ WF,
    unsigned* __restrict__ kvB, const int* __restrict__ eactp)
{
  if (blockIdx.x * 64 >= eactp[0]) return;
  __shared__ unsigned smem[4 * 1344];
  int tid = threadIdx.x;
  int w = __builtin_amdgcn_readfirstlane(tid >> 6);
  int l = tid & 63;
  int quad = l >> 4;
  int lo = l & 15;
  unsigned* WS  = smem + w * 1344;     // per-wave private region (5376 B)
  float*    xsS = (float*)WS;          // [0,320)    16 x 20 f32 x[src]
  unsigned* xsB = WS + 320;            // [320,512)  16 x 12 (8 used) bf16 pairs x
  unsigned* efB = WS + 512;            // [512,704)  16 x 12 bf16 pairs ef
  unsigned* h1P = WS + 704;            // [704,1024) 16 x 20 (16 used) pairs (m,m+16)
  unsigned* h2P = WS + 1024;           // [1024,1344) 16 x 20 channel-permuted pairs / f32 kv stage

  int ebw = blockIdx.x * 64 + w * 16;

  // ---- early independent global loads (off the critical chain) ----
  float b2a = B2[lo], b2b = B2[16 + lo];
  float scv[4];
#pragma unroll
  for (int r = 0; r < 4; r++) scv[r] = scaleP[ebw + quad * 4 + r];

  // ---- gather (4 lanes per edge, wave-local) ----
  {
    int e4 = l >> 2, c4 = l & 3;
    int s4 = srcP[ebw + e4];
    float4 xv4 = ((const float4*)(x + (size_t)s4 * 16))[c4];
    float4 ev4;
    if (MODE == 2) {
      ev4 = ((const float4*)(xsum + (size_t)s4 * 16))[c4];
      if (c4 == 3) ev4.w += distP[ebw + e4];
    }
    *(float4*)&xsS[e4 * 20 + c4 * 4] = xv4;
    uint2 xp; xp.x = pk2(xv4.x, xv4.y); xp.y = pk2(xv4.z, xv4.w);
    *(uint2*)&xsB[e4 * 12 + c4 * 2] = xp;
    if (MODE == 2) {
      uint2 ep; ep.x = pk2(ev4.x, ev4.y); ep.y = pk2(ev4.z, ev4.w);
      *(uint2*)&efB[e4 * 12 + c4 * 2] = ep;
    }
  }

  // ---- h1 -> h1P as bf16 pairs: dword d of row e holds (m=d, m=d+16) ----
  if (MODE == 0) {
    float dd = distP[ebw + lo];
#pragma unroll
    for (int jj = 0; jj < 4; jj++) {
      int d = quad * 4 + jj;
      float v0 = fmaxf(B1[d]      + dd * W1[15 * 32 + d],      0.f);
      float v1 = fmaxf(B1[d + 16] + dd * W1[15 * 32 + d + 16], 0.f);
      h1P[lo * 20 + d] = pk2(v0, v1);
    }
  } else {
    float b1a = B1[lo], b1b = B1[16 + lo];
    FragU a, b0, b1;
    uint4 r = *(const uint4*)&efB[lo * 12 + (quad & 1) * 4];
    uint4 z = make_uint4(0, 0, 0, 0);
    a.u = (quad >= 2) ? z : r;
    b0.u = WF[19 * 64 + l];
    b1.u = WF[20 * 64 + l];
    f32x4 c0 = {0.f, 0.f, 0.f, 0.f};
    f32x4 c1 = {0.f, 0.f, 0.f, 0.f};
    c0 = __builtin_amdgcn_mfma_f32_16x16x32_bf16(a.s, b0.s, c0, 0, 0, 0);
    c1 = __builtin_amdgcn_mfma_f32_16x16x32_bf16(a.s, b1.s, c1, 0, 0, 0);
#pragma unroll
    for (int r2 = 0; r2 < 4; r2++)
      h1P[(quad * 4 + r2) * 20 + lo] =
          pk2(fmaxf(c0[r2] + b1a, 0.f), fmaxf(c1[r2] + b1b, 0.f));
  }

  // ---- h2 via MFMA -> h2P channel-permuted: pos p=(c&1)*8+(c>>1) ----
  {
    FragU a, b0, b1;
    a.u = *(const uint4*)&h1P[lo * 20 + quad * 4];
    b0.u = WF[17 * 64 + l];
    b1.u = WF[18 * 64 + l];
    f32x4 hc0 = {0.f, 0.f, 0.f, 0.f};
    f32x4 hc1 = {0.f, 0.f, 0.f, 0.f};
    hc0 = __builtin_amdgcn_mfma_f32_16x16x32_bf16(a.s, b0.s, hc0, 0, 0, 0);
    hc1 = __builtin_amdgcn_mfma_f32_16x16x32_bf16(a.s, b1.s, hc1, 0, 0, 0);
    int pp = (lo & 1) * 8 + (lo >> 1);   // permuted position for channel c=lo
    float b2av = b2a, b2bv = b2b;
#pragma unroll
    for (int r = 0; r < 4; r++)
      h2P[(quad * 4 + r) * 20 + pp] =
          pk2(fmaxf(hc0[r] + b2av, 0.f), fmaxf(hc1[r] + b2bv, 0.f));
  }

  // ---- pull operands into registers ----
  // x half for this lane's i-range: i = (quad&1)*8 + j
  float2v xs2[4];
  {
    const float4* xr = (const float4*)&xsS[lo * 20 + (quad & 1) * 8];
#pragma unroll
    for (int i = 0; i < 2; i++) {
      float4 t = xr[i];
      float2v a; a.x = t.x; a.y = t.y;
      float2v b; b.x = t.z; b.y = t.w;
      xs2[2 * i]     = a;
      xs2[2 * i + 1] = b;
    }
  }
  // h2 dwords for this lane's m-parity (even for quads 0-1, odd for 2-3):
  // positions (quad>>1)*8 .. +7 of the permuted row.
  uint4 hq0 = *(const uint4*)&h2P[lo * 20 + (quad >> 1) * 8];
  uint4 hq1 = *(const uint4*)&h2P[lo * 20 + (quad >> 1) * 8 + 4];
  unsigned hdw[8] = {hq0.x, hq0.y, hq0.z, hq0.w, hq1.x, hq1.y, hq1.z, hq1.w};

  // ---- bias term: kv += x @ B3 ----
  f32x4 acc = {0.f, 0.f, 0.f, 0.f};
  {
    FragU a, b;
    uint4 r = *(const uint4*)&xsB[lo * 12 + (quad & 1) * 4];
    uint4 z = make_uint4(0, 0, 0, 0);
    a.u = (quad >= 2) ? z : r;
    b.u = WF[16 * 64 + l];
    acc = __builtin_amdgcn_mfma_f32_16x16x32_bf16(a.s, b.s, acc, 0, 0, 0);
  }

  // ---- 16 W3 MFMAs, A-fragments built in registers ----
  // fragment f: lane (quad,lo) supplies h2[2f+(quad>>1)] * x[(quad&1)*8+j].
  // h2 value: dword hdw[f&7], half = f>>3 (pos k holds channels (2k[+1], +16)).
#pragma unroll
  for (int f = 0; f < 16; f++) {
    float hm = xbf(hdw[f & 7], f >> 3);
    float2v hm2; hm2.x = hm; hm2.y = hm;
    float2v p0 = pkmul2(hm2, xs2[0]);
    float2v p1 = pkmul2(hm2, xs2[1]);
    float2v p2 = pkmul2(hm2, xs2[2]);
    float2v p3 = pkmul2(hm2, xs2[3]);
    FragU a, b;
    a.u.x = pk2(p0.x, p0.y);
    a.u.y = pk2(p1.x, p1.y);
    a.u.z = pk2(p2.x, p2.y);
    a.u.w = pk2(p3.x, p3.y);
    b.u = WF[f * 64 + l];
    acc = __builtin_amdgcn_mfma_f32_16x16x32_bf16(a.s, b.s, acc, 0, 0, 0);
  }

  // ---- kv epilogue: scale, stage f32 (reuse h2P), pack, coalesced store ----
#pragma unroll
  for (int r = 0; r < 4; r++) {
    int e = quad * 4 + r;
    ((float*)h2P)[e * 20 + lo] = acc[r] * (F_Y0 * scv[r]);
  }
  {
    int e2 = l >> 2, c = l & 3;
    const float* row = (const float*)&h2P[e2 * 20 + c * 4];
    float4 t = *(const float4*)row;
    uint2 pkd;
    pkd.x = pk2(t.x, t.y);
    pkd.y = pk2(t.z, t.w);
    *(uint2*)(kvB + ((size_t)(ebw + e2) * 8 + c * 2)) = pkd;
  }
}

// ---------------- fused softmax-gather + node update (16 threads/node) ------
// Degree loop software-pipelined 4-deep: 12 independent loads issue before
// the first exp consumes them.
template <bool INIT>
__global__ __launch_bounds__(256) void k_agg_update(
    const int* __restrict__ row_ptr, const float* __restrict__ scaleP,
    const unsigned* __restrict__ kvB, const float* __restrict__ qin,
    const float* __restrict__ xin,
    const float* __restrict__ Wproj, const float* __restrict__ Wq_next,
    float* __restrict__ xout, float* __restrict__ qout, float* __restrict__ xsum, int N)
{
  __shared__ float sA[16 * 8];
  __shared__ float sX[16 * 17];
  __shared__ float sN[16 * 17];
  int tid = threadIdx.x;
  int nl = tid >> 4;
  int t16 = tid & 15;
  int h = t16 & 7;
  int p = t16 >> 3;
  int n = blockIdx.x * 16 + nl;
  int hd = h >> 1, hh = h & 1;

  float qh = qin[(size_t)n * 8 + h];
  int j0 = row_ptr[n], j1 = row_ptr[n + 1];
  float num = 0.f, den = 0.f;
  int j = j0 + p;
  for (; j + 6 < j1; j += 8) {
    unsigned va = kvB[(size_t)j * 8 + hd];
    unsigned ka = kvB[(size_t)j * 8 + 4 + hd];
    unsigned vb = kvB[(size_t)(j + 2) * 8 + hd];
    unsigned kb = kvB[(size_t)(j + 2) * 8 + 4 + hd];
    unsigned vc = kvB[(size_t)(j + 4) * 8 + hd];
    unsigned kc = kvB[(size_t)(j + 4) * 8 + 4 + hd];
    unsigned vd = kvB[(size_t)(j + 6) * 8 + hd];
    unsigned kd = kvB[(size_t)(j + 6) * 8 + 4 + hd];
    float sa = scaleP[j];
    float sb = scaleP[j + 2];
    float sc = scaleP[j + 4];
    float sd = scaleP[j + 6];
    float wa = sa * __expf(fminf(xbf(ka, hh) * qh, 60.0f));
    float wb = sb * __expf(fminf(xbf(kb, hh) * qh, 60.0f));
    float wc = sc * __expf(fminf(xbf(kc, hh) * qh, 60.0f));
    float wd = sd * __expf(fminf(xbf(kd, hh) * qh, 60.0f));
    num += wa * xbf(va, hh) + wb * xbf(vb, hh) + wc * xbf(vc, hh) + wd * xbf(vd, hh);
    den += (wa + wb) + (wc + wd);
  }
  for (; j < j1; j += 2) {
    float val = xbf(kvB[(size_t)j * 8 + hd], hh);
    float key = xbf(kvB[(size_t)j * 8 + 4 + hd], hh);
    float lg = fminf(key * qh, 60.0f);
    float wv = scaleP[j] * __expf(lg);
    num += wv * val;
    den += wv;
  }
  num += __shfl_xor(num, 8, 64);
  den += __shfl_xor(den, 8, 64);
  if (p == 0) sA[nl * 8 + h] = num / fmaxf(den, 1e-20f);
  sX[nl * 17 + t16] = xin[(size_t)n * 16 + t16];
  __syncthreads();

  float cat[24];
#pragma unroll
  for (int jj = 0; jj < 8; jj++) cat[jj] = sA[nl * 8 + jj];
#pragma unroll
  for (int jj = 0; jj < 16; jj++) cat[8 + jj] = sX[nl * 17 + jj];
  float xn = 0.f;
#pragma unroll
  for (int jj = 0; jj < 24; jj++) xn += Wproj[t16 * 24 + jj] * cat[jj];
  xout[(size_t)n * 16 + t16] = xn;
  if (INIT) {
    xsum[(size_t)n * 16 + t16] = xn;
  } else {
    xsum[(size_t)n * 16 + t16] += xn;
  }
  sN[nl * 17 + t16] = xn;
  __syncthreads();

  if (p == 0) {
    float a = 0.f;
#pragma unroll
    for (int i = 0; i < 16; i++) a += Wq_next[h * 16 + i] * sN[nl * 17 + i];
    qout[(size_t)n * 8 + h] = a;
  }
}

// ---------------- fused feats gather + final MLP (16 threads/node) ----------
// Gather loop batched 4-deep for load ILP.
__global__ __launch_bounds__(256) void k_feats_final(
    const int* __restrict__ row_ptr, const unsigned* __restrict__ kvB,
    const float* __restrict__ x,
    const int* __restrict__ species, const float* __restrict__ emb,
    const float* __restrict__ Wself,
    const float* __restrict__ mW1, const float* __restrict__ mb1,
    const float* __restrict__ mW2, const float* __restrict__ mb2,
    const float* __restrict__ mW3, const float* __restrict__ mb3,
    float* __restrict__ learn_part, int N)
{
  __shared__ float sX[16 * 20];
  __shared__ float sC[16 * 40];
  __shared__ float sH[16 * 20];
  int tid = threadIdx.x;
  int nl = tid >> 4;
  int o = tid & 15;
  int n = blockIdx.x * 16 + nl;
  int od = o >> 1, oh = o & 1;

  int j0 = row_ptr[n], j1 = row_ptr[n + 1];
  float ft = 0.f;
  int j = j0;
  for (; j + 3 < j1; j += 4) {
    unsigned a = kvB[(size_t)j * 8 + od];
    unsigned b = kvB[(size_t)(j + 1) * 8 + od];
    unsigned c = kvB[(size_t)(j + 2) * 8 + od];
    unsigned d = kvB[(size_t)(j + 3) * 8 + od];
    ft += (xbf(a, oh) + xbf(b, oh)) + (xbf(c, oh) + xbf(d, oh));
  }
  for (; j < j1; ++j) ft += xbf(kvB[(size_t)j * 8 + od], oh);

  if (o < 4) {
    float4 v = ((const float4*)(x + (size_t)n * 16))[o];
    *(float4*)&sX[nl * 20 + o * 4] = v;
  } else if (o < 8) {
    int sp = species[n] - 1;
    float4 v = ((const float4*)(emb + (size_t)sp * 16))[o - 4];
    *(float4*)&sC[nl * 40 + (o - 4) * 4] = v;
  }
  __syncthreads();

  float xv[16];
  load16(&sX[nl * 20], xv);
  float a = ft;
#pragma unroll
  for (int i = 0; i < 16; i++) a += Wself[o * 16 + i] * xv[i];
  sC[nl * 40 + 16 + o] = a;
  __syncthreads();

  float cat[32];
  load16(&sC[nl * 40], cat);
  load16(&sC[nl * 40 + 16], cat + 16);
  float hh = mb1[o];
#pragma unroll
  for (int k = 0; k < 32; k++) hh += cat[k] * mW1[k * 16 + o];
  hh = siluf(hh);
  sH[nl * 20 + o] = hh;
  __syncthreads();

  float hv[16];
  load16(&sH[nl * 20], hv);
  float h2 = mb2[o];
#pragma unroll
  for (int k = 0; k < 16; k++) h2 += hv[k] * mW2[k * 16 + o];
  h2 = siluf(h2);
  float contrib = h2 * mW3[o] + ((o == 0) ? mb3[0] : 0.f);
  block_reduce_store(contrib, learn_part);
}

// ---------------- final reduction ----------------
__global__ __launch_bounds__(256) void k_finalize(
    const float* __restrict__ coul_part, int nc,
    const float* __restrict__ learn_part, int nl,
    float* __restrict__ out)
{
  __shared__ float sred[4];
  int tid = threadIdx.x;
  float v = 0.f;
  for (int i = tid; i < nc; i += 256) v += coul_part[i];
  for (int i = tid; i < nl; i += 256) v += learn_part[i];
#pragma unroll
  for (int off = 32; off > 0; off >>= 1) v += __shfl_down(v, off, 64);
  if ((tid & 63) == 0) sred[tid >> 6] = v;
  __syncthreads();
  if (tid == 0) out[0] = sred[0] + sred[1] + sred[2] + sred[3];
}

extern "C" void kernel_launch(void* const* d_in, const int* in_sizes, int n_in,
                              void* d_out, int out_size, void* d_ws, size_t ws_size,
                              hipStream_t stream)
{
  const int*   species = (const int*)d_in[0];
  const int*   src     = (const int*)d_in[1];
  const int*   dst     = (const int*)d_in[2];
  const float* rel_pos = (const float*)d_in[3];
  const float* emb     = (const float*)d_in[4];
  const float* kv_W1   = (const float*)d_in[5];
  const float* kv_b1   = (const float*)d_in[6];
  const float* kv_W2   = (const float*)d_in[7];
  const float* kv_b2   = (const float*)d_in[8];
  const float* kv_W3   = (const float*)d_in[9];
  const float* kv_b3   = (const float*)d_in[10];
  const float* Wq      = (const float*)d_in[11];
  const float* Wproj   = (const float*)d_in[12];
  const float* fin_W1  = (const float*)d_in[13];
  const float* fin_b1  = (const float*)d_in[14];
  const float* fin_W2  = (const float*)d_in[15];
  const float* fin_b2  = (const float*)d_in[16];
  const float* fin_W3  = (const float*)d_in[17];
  const float* fin_b3  = (const float*)d_in[18];
  const float* Wself   = (const float*)d_in[19];
  const float* mlp_W1  = (const float*)d_in[20];
  const float* mlp_b1  = (const float*)d_in[21];
  const float* mlp_W2  = (const float*)d_in[22];
  const float* mlp_b2  = (const float*)d_in[23];
  const float* mlp_W3  = (const float*)d_in[24];
  const float* mlp_b3  = (const float*)d_in[25];

  const int N = in_sizes[0];
  const int E = in_sizes[1];
  const int nblk_e = (E + 255) / 256;
  const int nblk_n = (N + 255) / 256;
  const int nblk_f = N / 16;

  char* p = (char*)d_ws;
  auto alloc = [&](size_t bytes) -> void* {
    void* r = (void*)p;
    p += (bytes + 255) & ~(size_t)255;
    return r;
  };
  float*    dist_   = (float*)alloc((size_t)E * 4);
  float*    scale_  = (float*)alloc((size_t)E * 4);
  float*    distP   = (float*)alloc((size_t)E * 4);
  float*    scaleP  = (float*)alloc((size_t)E * 4);
  int*      srcP    = (int*)  alloc((size_t)E * 4);
  int*      perm    = (int*)  alloc((size_t)E * 4);
  unsigned* kvB     = (unsigned*)alloc((size_t)E * 8 * 4);
  float*    xA      = (float*)alloc((size_t)N * 16 * 4);
  float*    xB      = (float*)alloc((size_t)N * 16 * 4);
  float*    xsum    = (float*)alloc((size_t)N * 16 * 4);
  float*    q       = (float*)alloc((size_t)N * 8 * 4);
  int*      cnt     = (int*)  alloc((size_t)N * 4);
  int*      row_ptr = (int*)  alloc((size_t)(N + 1) * 4);
  int*      row_cur = (int*)  alloc((size_t)N * 4);
  int*      bsum    = (int*)  alloc(128 * 4);
  int*      boff    = (int*)  alloc(128 * 4);
  uint4*    WF      = (uint4*)alloc((size_t)5 * 21 * 64 * 16);
  float*    coul_part  = (float*)alloc((size_t)nblk_e * 4);
  float*    learn_part = (float*)alloc((size_t)nblk_f * 4);

  const int* eactp = row_ptr + N;   // row_ptr[N] = number of live edges

  dim3 blk(256);
  dim3 egrid(nblk_e);
  dim3 cgrid(E / 64);
  dim3 ngrid(nblk_n);
  dim3 augrid(N / 16);
  dim3 fgrid(nblk_f);

  hipMemsetAsync(cnt, 0, (size_t)N * 4, stream);

  k_prepack<<<dim3(27), blk, 0, stream>>>(kv_W3, kv_b3, fin_W3, fin_b3,
                                          kv_W2, fin_W2, kv_W1, fin_W1, WF);

  k_pre<<<egrid, blk, 0, stream>>>(species, src, dst, rel_pos, dist_, scale_,
                                   cnt, coul_part, srcP, distP, scaleP, E);
  k_scan1<<<ngrid, blk, 0, stream>>>(cnt, row_ptr, bsum);
  k_scan2<<<dim3(1), dim3(128), 0, stream>>>(bsum, boff);
  k_scan3<<<ngrid, blk, 0, stream>>>(row_ptr, row_cur, boff, cnt, N);
  k_scatter_perm<<<egrid, blk, 0, stream>>>(dst, scale_, row_cur, perm, E);
  k_permute<<<egrid, blk, 0, stream>>>(perm, src, dist_, scale_,
                                       srcP, distP, scaleP, eactp);

  k_node_init<<<ngrid, blk, 0, stream>>>(species, emb, Wq, xA, q, N);

  float* xin = xA;
  float* xout = xB;
  for (int l = 0; l < 4; l++) {
    const float* W1 = kv_W1 + (size_t)l * 16 * 32;
    const float* B1 = kv_b1 + (size_t)l * 32;
    const float* B2 = kv_b2 + (size_t)l * 32;
    const uint4* WFl = WF + (size_t)l * 21 * 64;
    const float* Wqn = Wq + (size_t)((l < 3) ? (l + 1) : 0) * 8 * 16;
    if (l == 0) {
      k_edge_conv<0><<<cgrid, blk, 0, stream>>>(srcP, scaleP, distP, xsum, xin,
                                                W1, B1, B2, WFl, kvB, eactp);
    } else {
      k_edge_conv<2><<<cgrid, blk, 0, stream>>>(srcP, scaleP, distP, xsum, xin,
                                                W1, B1, B2, WFl, kvB, eactp);
    }
    if (l == 0) {
      k_agg_update<true><<<augrid, blk, 0, stream>>>(row_ptr, scaleP, kvB, q, xin,
                                                     Wproj, Wqn, xout, q, xsum, N);
    } else {
      k_agg_update<false><<<augrid, blk, 0, stream>>>(row_ptr, scaleP, kvB, q, xin,
                                                      Wproj + (size_t)l * 16 * 24, Wqn,
                                                      xout, q, xsum, N);
    }
    float* tmp = xin; xin = xout; xout = tmp;
  }

  k_edge_conv<2><<<cgrid, blk, 0, stream>>>(srcP, scaleP, distP, xsum, xin,
                                            fin_W1, fin_b1, fin_b2,
                                            WF + (size_t)4 * 21 * 64, kvB, eactp);
  k_feats_final<<<fgrid, blk, 0, stream>>>(row_ptr, kvB, xin, species, emb, Wself,
                                           mlp_W1, mlp_b1, mlp_W2, mlp_b2, mlp_W3, mlp_b3,
                                           learn_part, N);
  k_finalize<<<dim3(1), blk, 0, stream>>>(coul_part, nblk_e, learn_part, nblk_f,
                                          (float*)d_out);
}